// Round 5
// baseline (118766.516 us; speedup 1.0000x reference)
//
#include <hip/hip_runtime.h>

#define DEV static __device__ __forceinline__

// fp32 arena: flag(256) + x(38,535,168) + h(38,535,168) + s1(154,140,672) + q(19,267,584)
#define ARENA_BYTES 250480384ULL
__device__ __align__(256) char g_arena[ARENA_BYTES];

DEV float gelu_tanh(float x) {
    float x3 = x * x * x;
    return 0.5f * x * (1.f + tanhf(0.7978845608028654f * (x + 0.044715f * x3)));
}

// ---- target_positions dtype sniff: int64 iff ALL odd int32 slots are 0 ----
// (reads pos[2i+1], i<3136 -> max idx 6271: in-bounds for int32(6272) and int64(12544 slots))
__global__ __launch_bounds__(256) void k_detect_i64(const int* __restrict__ pos, int nhalf,
                                                    int* __restrict__ flagD) {
    int i = blockIdx.x * 256 + threadIdx.x;
    if (i < nhalf && pos[2 * i + 1] != 0) atomicAnd(flagD, 0);
}

// ---- gather rows of spatial_pos_embed (dtype-robust, clamped) ----
__global__ __launch_bounds__(256) void k_gather32(const float* __restrict__ spe,
                                                  const int* __restrict__ pos,
                                                  const int* __restrict__ flagD,
                                                  float* __restrict__ qf) {
    int row = blockIdx.x;
    int p = (*flagD) ? pos[2 * row] : pos[row];
    p = (p < 0) ? 0 : (p > 195 ? 195 : p);
    const float* src = spe + (size_t)p * 768;
    size_t o = (size_t)row * 768;
    for (int i = threadIdx.x; i < 768; i += 256) qf[o + i] = src[i];
}

// ---- LayerNorm over 768, fp32 -> fp32, one block per row ----
__global__ __launch_bounds__(256) void k_ln32(const float* __restrict__ X,
                                              const float* __restrict__ g,
                                              const float* __restrict__ b,
                                              float* __restrict__ Of) {
    const int row = blockIdx.x, tid = threadIdx.x;
    const float* xr = X + (size_t)row * 768;
    float v0 = xr[tid], v1 = xr[tid + 256], v2 = xr[tid + 512];
    float s = v0 + v1 + v2, s2 = v0 * v0 + v1 * v1 + v2 * v2;
#pragma unroll
    for (int off = 32; off; off >>= 1) {
        s += __shfl_xor(s, off);
        s2 += __shfl_xor(s2, off);
    }
    __shared__ float red[8];
    const int wid = tid >> 6, lane = tid & 63;
    if (lane == 0) { red[wid] = s; red[4 + wid] = s2; }
    __syncthreads();
    s = red[0] + red[1] + red[2] + red[3];
    s2 = red[4] + red[5] + red[6] + red[7];
    const float mu = s * (1.f / 768.f);
    const float var = fmaxf(s2 * (1.f / 768.f) - mu * mu, 0.f);
    const float rs = rsqrtf(var + 1e-5f);
    size_t o = (size_t)row * 768;
#pragma unroll
    for (int i = 0; i < 3; ++i) {
        int c = tid + 256 * i;
        float vv = (i == 0 ? v0 : (i == 1 ? v1 : v2));
        Of[o + c] = (vv - mu) * rs * g[c] + b[c];
    }
}

// ---- fp32 reference GEMM: C[M,N] = A[M,K] @ W[K,N] + bias (+gelu/+res) ----
// block = 256 thr: 4 m-rows (one per wave) x 64 n-cols. W read directly (no transpose).
template <bool GELU_, bool RES_>
__global__ __launch_bounds__(256) void k_gemm32(const float* __restrict__ A,
                                                const float* __restrict__ W,
                                                const float* __restrict__ bias,
                                                const float* __restrict__ R,
                                                float* __restrict__ C,
                                                int M, int N, int K) {
    const int tid = threadIdx.x;
    const int n = blockIdx.x * 64 + (tid & 63);
    const int m = blockIdx.y * 4 + (tid >> 6);
    const float* a = A + (size_t)m * K;
    const float* w = W + n;
    float acc = 0.f;
#pragma unroll 8
    for (int k = 0; k < K; ++k) acc = fmaf(a[k], w[(size_t)k * N], acc);
    float v = acc + bias[n];
    if (GELU_) v = gelu_tanh(v);
    if (RES_)  v += R[(size_t)m * N + n];
    C[(size_t)m * N + n] = v;
}

// ---- fp32 attention, one block per (b,h), shuffle-only (zero LDS) ----
__global__ __launch_bounds__(256) void k_attn32(const float* __restrict__ Qp, int qs,
                                                const float* __restrict__ Kp, int ks,
                                                const float* __restrict__ Vp, int vs,
                                                float* __restrict__ Op, int os,
                                                int Tq, int Tk) {
    const int bh = blockIdx.x, b = bh / 12, h = bh % 12;
    const int tid = threadIdx.x, lane = tid & 63, wid = tid >> 6;

    for (int tq = wid; tq < Tq; tq += 4) {
        const float qv = Qp[((size_t)b * Tq + tq) * qs + h * 64 + lane];
        float sj[4];
        int tkj[4];
#pragma unroll
        for (int j = 0; j < 4; ++j) {
            sj[j] = 0.f;
            int t_ = lane + 64 * j;
            tkj[j] = (t_ < Tk) ? t_ : 0;
        }
        for (int d = 0; d < 64; ++d) {
            const float qd = __shfl(qv, d);
#pragma unroll
            for (int j = 0; j < 4; ++j)
                sj[j] = fmaf(qd, Kp[((size_t)b * Tk + tkj[j]) * ks + h * 64 + d], sj[j]);
        }
        float mx = -1e30f;
#pragma unroll
        for (int j = 0; j < 4; ++j) {
            sj[j] *= 0.125f;                       // 1/sqrt(64)
            if (lane + 64 * j < Tk) mx = fmaxf(mx, sj[j]);
        }
#pragma unroll
        for (int off = 32; off; off >>= 1) mx = fmaxf(mx, __shfl_xor(mx, off));
        float sum = 0.f;
#pragma unroll
        for (int j = 0; j < 4; ++j) {
            float w = (lane + 64 * j < Tk) ? __expf(sj[j] - mx) : 0.f;
            sj[j] = w;
            sum += w;
        }
#pragma unroll
        for (int off = 32; off; off >>= 1) sum += __shfl_xor(sum, off);

        float o = 0.f;
        for (int j = 0; j < 4; ++j) {
            for (int t2 = 0; t2 < 64; ++t2) {
                int tk = t2 + 64 * j;        // uniform across lanes
                if (tk >= Tk) break;
                float w = __shfl(sj[j], t2); // full-wave shuffle before any divergence
                o = fmaf(w, Vp[((size_t)b * Tk + tk) * vs + h * 64 + lane], o);
            }
        }
        o /= sum;
        Op[((size_t)b * Tq + tq) * os + h * 64 + lane] = o;
    }
}

// =======================================================================================
extern "C" void kernel_launch(void* const* d_in, const int* in_sizes, int n_in,
                              void* d_out, int out_size, void* d_ws, size_t ws_size,
                              hipStream_t stream) {
    const int D = 768, FF = 3072, NB = 64, S = 196, T = 98, NL = 3;
    const int Menc = NB * S;   // 12544
    const int Mdec = NB * T;   // 6272

    auto IN = [&](int i) { return (const float*)d_in[i]; };
    const float* ctx = IN(0);
    const int* tpos = (const int*)d_in[1];
    const float* spe = IN(2);
    const float* norm_g = IN(3);
    const float* norm_b = IN(4);

    char* base;
    if (ws_size >= ARENA_BYTES) {
        base = (char*)d_ws;
    } else {
        void* sym = nullptr;
        if (hipGetSymbolAddress(&sym, HIP_SYMBOL(g_arena)) == hipSuccess && sym)
            base = (char*)sym;
        else
            base = (char*)d_ws;
    }
    char* pp = base;
    auto alloc = [&](long long bytes) -> void* {
        void* r = (void*)pp;
        pp += (bytes + 255) & ~255LL;
        return r;
    };
    int* flag = (int*)alloc(256);
    int* flagD = flag + 1;                                   // byte offset 4: INSIDE the slot
    float* x = (float*)alloc((long long)Menc * D * 4);       // encoder residual stream
    float* h = (float*)alloc((long long)Menc * D * 4);       // LN out / attn out (aliased)
    float* s1 = (float*)alloc((long long)Menc * FF * 4);     // qkv / ff1 / dec qq,kk,vv
    float* q = (float*)alloc((long long)Mdec * D * 4);       // decoder residual stream

    hipMemsetAsync(flagD, 0x01, 4, stream);                  // presume int64
    k_detect_i64<<<dim3((Mdec / 2 + 255) / 256), dim3(256), 0, stream>>>(tpos, Mdec / 2, flagD);

    auto gemm = [&](int mode, const float* A, const float* W, const float* bias,
                    const float* R, float* C, int M, int N, int K) {
        dim3 g(N / 64, M / 4), blk(256);
        if (mode == 0)      k_gemm32<false, false><<<g, blk, 0, stream>>>(A, W, bias, nullptr, C, M, N, K);
        else if (mode == 1) k_gemm32<false, true><<<g, blk, 0, stream>>>(A, W, bias, R, C, M, N, K);
        else                k_gemm32<true, false><<<g, blk, 0, stream>>>(A, W, bias, nullptr, C, M, N, K);
    };
    auto ln = [&](const float* X, const float* gg, const float* bb, float* Of, int M) {
        k_ln32<<<dim3(M), dim3(256), 0, stream>>>(X, gg, bb, Of);
    };
    auto attn = [&](const float* Q, int qs, const float* Kp, int ks2, const float* Vp, int vs,
                    float* O, int Tq, int Tk) {
        k_attn32<<<dim3(NB * 12), dim3(256), 0, stream>>>(Q, qs, Kp, ks2, Vp, vs, O, D, Tq, Tk);
    };

    // pre-norm transformer block (self-attn + GELU MLP, residuals); Xf updated in place
    auto tblock = [&](float* Xf, int Mtok, int Tseq, int basei, int l) {
        const float* ln1g = IN(basei + 0) + l * D;
        const float* ln1b = IN(basei + 1) + l * D;
        const float* wqkv = IN(basei + 2) + (long long)l * D * 3 * D;
        const float* bqkv = IN(basei + 3) + l * 3 * D;
        const float* wo = IN(basei + 4) + (long long)l * D * D;
        const float* bo = IN(basei + 5) + l * D;
        const float* ln2g = IN(basei + 6) + l * D;
        const float* ln2b = IN(basei + 7) + l * D;
        const float* w1 = IN(basei + 8) + (long long)l * D * FF;
        const float* b1 = IN(basei + 9) + l * FF;
        const float* w2 = IN(basei + 10) + (long long)l * FF * D;
        const float* b2 = IN(basei + 11) + l * D;

        ln(Xf, ln1g, ln1b, h, Mtok);
        gemm(0, h, wqkv, bqkv, nullptr, s1, Mtok, 3 * D, D);             // qkv
        attn(s1, 3 * D, s1 + D, 3 * D, s1 + 2 * D, 3 * D, h, Tseq, Tseq);// self-attn -> h
        gemm(1, h, wo, bo, Xf, Xf, Mtok, D, D);                          // x += ao@wo+bo
        ln(Xf, ln2g, ln2b, h, Mtok);
        gemm(2, h, w1, b1, nullptr, s1, Mtok, FF, D);                    // gelu(h@w1+b1)
        gemm(1, s1, w2, b2, Xf, Xf, Mtok, D, FF);                        // x += ff@w2+b2
    };

    // ---------------- encoder ----------------
    hipMemcpyAsync(x, ctx, (long long)Menc * D * 4, hipMemcpyDeviceToDevice, stream);
    for (int l = 0; l < NL; ++l)
        tblock(x, Menc, S, 5, l);

    // ---------------- decoder ----------------
    k_gather32<<<dim3(Mdec), dim3(256), 0, stream>>>(spe, tpos, flagD, q);
    float* qq = s1;
    float* kk = s1 + (long long)Mdec * D;
    float* vv = kk + (long long)Menc * D;
    for (int l = 0; l < NL; ++l) {
        gemm(0, q, IN(29) + (long long)l * D * D, IN(30) + l * D, nullptr, qq, Mdec, D, D);
        gemm(0, x, IN(31) + (long long)l * D * D, IN(32) + l * D, nullptr, kk, Menc, D, D);
        gemm(0, x, IN(33) + (long long)l * D * D, IN(34) + l * D, nullptr, vv, Menc, D, D);
        attn(qq, D, kk, D, vv, D, h, T, S);                              // cross-attn -> h
        gemm(0, h, IN(35) + (long long)l * D * D, IN(36) + l * D, nullptr, q, Mdec, D, D);
        tblock(q, Mdec, T, 17, l);
    }
    ln(q, norm_g, norm_b, (float*)d_out, Mdec);
}

// Round 7
// 21235.478 us; speedup vs baseline: 5.5928x; 5.5928x over previous
//
#include <hip/hip_runtime.h>

typedef unsigned short u16;
typedef __attribute__((ext_vector_type(8))) __bf16 bf16x8;
typedef __attribute__((ext_vector_type(4))) float f32x4;

#define DEV static __device__ __forceinline__

// fp32 arena + bf16 weight scratch
#define ARENA_BYTES 255197440ULL
__device__ __align__(256) char g_arena[ARENA_BYTES];

DEV float bf2f(u16 u) { return __uint_as_float(((unsigned)u) << 16); }
DEV u16 f2bf(float f) {
    unsigned u = __float_as_uint(f);
    return (u16)((u + 0x7fffu + ((u >> 16) & 1u)) >> 16);
}
DEV float gelu_tanh(float x) {
    float x3 = x * x * x;
    return 0.5f * x * (1.f + tanhf(0.7978845608028654f * (x + 0.044715f * x3)));
}

// ---- target_positions dtype sniff: int64 iff ALL odd int32 slots are 0 ----
__global__ __launch_bounds__(256) void k_detect_i64(const int* __restrict__ pos, int nhalf,
                                                    int* __restrict__ flagD) {
    int i = blockIdx.x * 256 + threadIdx.x;
    if (i < nhalf && pos[2 * i + 1] != 0) atomicAnd(flagD, 0);
}

// ---- gather rows of spatial_pos_embed (dtype-robust, clamped) ----
__global__ __launch_bounds__(256) void k_gather32(const float* __restrict__ spe,
                                                  const int* __restrict__ pos,
                                                  const int* __restrict__ flagD,
                                                  float* __restrict__ qf) {
    int row = blockIdx.x;
    int p = (*flagD) ? pos[2 * row] : pos[row];
    p = (p < 0) ? 0 : (p > 195 ? 195 : p);
    const float* src = spe + (size_t)p * 768;
    size_t o = (size_t)row * 768;
    for (int i = threadIdx.x; i < 768; i += 256) qf[o + i] = src[i];
}

// ---- LayerNorm over 768, fp32 -> fp32, one block per row ----
__global__ __launch_bounds__(256) void k_ln32(const float* __restrict__ X,
                                              const float* __restrict__ g,
                                              const float* __restrict__ b,
                                              float* __restrict__ Of) {
    const int row = blockIdx.x, tid = threadIdx.x;
    const float* xr = X + (size_t)row * 768;
    float v0 = xr[tid], v1 = xr[tid + 256], v2 = xr[tid + 512];
    float s = v0 + v1 + v2, s2 = v0 * v0 + v1 * v1 + v2 * v2;
#pragma unroll
    for (int off = 32; off; off >>= 1) {
        s += __shfl_xor(s, off);
        s2 += __shfl_xor(s2, off);
    }
    __shared__ float red[8];
    const int wid = tid >> 6, lane = tid & 63;
    if (lane == 0) { red[wid] = s; red[4 + wid] = s2; }
    __syncthreads();
    s = red[0] + red[1] + red[2] + red[3];
    s2 = red[4] + red[5] + red[6] + red[7];
    const float mu = s * (1.f / 768.f);
    const float var = fmaxf(s2 * (1.f / 768.f) - mu * mu, 0.f);
    const float rs = rsqrtf(var + 1e-5f);
    size_t o = (size_t)row * 768;
#pragma unroll
    for (int i = 0; i < 3; ++i) {
        int c = tid + 256 * i;
        float vv = (i == 0 ? v0 : (i == 1 ? v1 : v2));
        Of[o + c] = (vv - mu) * rs * g[c] + b[c];
    }
}

// ---- weight transpose + fp32->bf16 convert: W[K,N] -> WT[N,K] ----
__global__ __launch_bounds__(256) void k_wtrans(const float* __restrict__ W,
                                                u16* __restrict__ WT, int K, int N) {
    int idx = blockIdx.x * 256 + threadIdx.x;
    int tot = N * (K >> 3);
    if (idx >= tot) return;
    int n = idx % N;
    int kc = idx / N;
    union { u16 u[8]; int4 v; } tmp;
#pragma unroll
    for (int j = 0; j < 8; ++j) tmp.u[j] = f2bf(W[(size_t)(kc * 8 + j) * N + n]);
    *(int4*)&WT[(size_t)n * K + kc * 8] = tmp.v;
}

// ---- MFMA GEMM, fp32 in / fp32 out: C[M,N] = A32[M,K] @ BT[N,K]^T + bias (+gelu/+res) ----
// 128x128 tile, BK=32, 4 waves (2x2), each wave 64x64 = 4x4 frags of 16x16x32 bf16.
// A is fp32 in global; converted to bf16 during LDS staging. BT is bf16 (from k_wtrans).
template <bool GELU_, bool RES_>
__global__ __launch_bounds__(256) void k_gemmM(const float* __restrict__ A,
                                               const u16* __restrict__ BT,
                                               const float* __restrict__ bias,
                                               const float* __restrict__ R,
                                               float* __restrict__ C,
                                               int M, int N, int K) {
    __shared__ __align__(16) u16 Asm[128 * 32];
    __shared__ __align__(16) u16 Bsm[128 * 32];
    const int tid = threadIdx.x;
    const int lane = tid & 63;
    const int wid = tid >> 6;
    const int wm = wid >> 1, wn = wid & 1;
    const size_t Abase = (size_t)blockIdx.x * 128 * K;   // float elements
    const size_t Bbase = (size_t)blockIdx.y * 128 * K;   // u16 elements

    f32x4 acc[4][4] = {};
    const int r0 = tid >> 2;             // A/B row this thread stages
    const int ko0 = (tid & 3) * 8;       // k-offset within 32-tile

    for (int k0 = 0; k0 < K; k0 += 32) {
        // A: load 8 fp32, convert to bf16, store 16B to LDS (rows r0 and r0+64)
        const float* Ag0 = A + Abase + (size_t)r0 * K + k0 + ko0;
        const float* Ag1 = Ag0 + (size_t)64 * K;
        {
            float4 a0 = *(const float4*)Ag0, a1 = *(const float4*)(Ag0 + 4);
            union { u16 u[8]; int4 v; } t;
            t.u[0] = f2bf(a0.x); t.u[1] = f2bf(a0.y); t.u[2] = f2bf(a0.z); t.u[3] = f2bf(a0.w);
            t.u[4] = f2bf(a1.x); t.u[5] = f2bf(a1.y); t.u[6] = f2bf(a1.z); t.u[7] = f2bf(a1.w);
            *(int4*)&Asm[tid * 8] = t.v;
        }
        {
            float4 a0 = *(const float4*)Ag1, a1 = *(const float4*)(Ag1 + 4);
            union { u16 u[8]; int4 v; } t;
            t.u[0] = f2bf(a0.x); t.u[1] = f2bf(a0.y); t.u[2] = f2bf(a0.z); t.u[3] = f2bf(a0.w);
            t.u[4] = f2bf(a1.x); t.u[5] = f2bf(a1.y); t.u[6] = f2bf(a1.z); t.u[7] = f2bf(a1.w);
            *(int4*)&Asm[(256 + tid) * 8] = t.v;
        }
        // B: bf16 direct
        const u16* Bg = BT + Bbase + (size_t)r0 * K + k0 + ko0;
        *(int4*)&Bsm[tid * 8] = *(const int4*)Bg;
        *(int4*)&Bsm[(256 + tid) * 8] = *(const int4*)(Bg + (size_t)64 * K);
        __syncthreads();

        const int fr = lane & 15, g = lane >> 4;
        bf16x8 af[4], bfr[4];
#pragma unroll
        for (int i = 0; i < 4; ++i) {
            af[i] = *(const bf16x8*)&Asm[(wm * 64 + i * 16 + fr) * 32 + g * 8];
            bfr[i] = *(const bf16x8*)&Bsm[(wn * 64 + i * 16 + fr) * 32 + g * 8];
        }
#pragma unroll
        for (int i = 0; i < 4; ++i)
#pragma unroll
            for (int j = 0; j < 4; ++j)
                acc[i][j] = __builtin_amdgcn_mfma_f32_16x16x32_bf16(af[i], bfr[j], acc[i][j], 0, 0, 0);
        __syncthreads();
    }

    // C/D layout: col=lane&15, row=(lane>>4)*4+reg  [HW-verified m89/m91]
    const int fr = lane & 15, g4 = (lane >> 4) * 4;
#pragma unroll
    for (int j = 0; j < 4; ++j) {
        const int col = blockIdx.y * 128 + wn * 64 + j * 16 + fr;
        const float bc = bias[col];
#pragma unroll
        for (int i = 0; i < 4; ++i) {
#pragma unroll
            for (int r = 0; r < 4; ++r) {
                const int row = blockIdx.x * 128 + wm * 64 + i * 16 + g4 + r;
                float v = acc[i][j][r] + bc;
                if (GELU_) v = gelu_tanh(v);
                if (RES_)  v += R[(size_t)row * N + col];
                C[(size_t)row * N + col] = v;
            }
        }
    }
}

// ---- fp32 attention, one block per (b,h), shuffle-only (known-good from round 5) ----
__global__ __launch_bounds__(256) void k_attn32(const float* __restrict__ Qp, int qs,
                                                const float* __restrict__ Kp, int ks,
                                                const float* __restrict__ Vp, int vs,
                                                float* __restrict__ Op, int os,
                                                int Tq, int Tk) {
    const int bh = blockIdx.x, b = bh / 12, h = bh % 12;
    const int tid = threadIdx.x, lane = tid & 63, wid = tid >> 6;

    for (int tq = wid; tq < Tq; tq += 4) {
        const float qv = Qp[((size_t)b * Tq + tq) * qs + h * 64 + lane];
        float sj[4];
        int tkj[4];
#pragma unroll
        for (int j = 0; j < 4; ++j) {
            sj[j] = 0.f;
            int t_ = lane + 64 * j;
            tkj[j] = (t_ < Tk) ? t_ : 0;
        }
        for (int d = 0; d < 64; ++d) {
            const float qd = __shfl(qv, d);
#pragma unroll
            for (int j = 0; j < 4; ++j)
                sj[j] = fmaf(qd, Kp[((size_t)b * Tk + tkj[j]) * ks + h * 64 + d], sj[j]);
        }
        float mx = -1e30f;
#pragma unroll
        for (int j = 0; j < 4; ++j) {
            sj[j] *= 0.125f;                       // 1/sqrt(64)
            if (lane + 64 * j < Tk) mx = fmaxf(mx, sj[j]);
        }
#pragma unroll
        for (int off = 32; off; off >>= 1) mx = fmaxf(mx, __shfl_xor(mx, off));
        float sum = 0.f;
#pragma unroll
        for (int j = 0; j < 4; ++j) {
            float w = (lane + 64 * j < Tk) ? __expf(sj[j] - mx) : 0.f;
            sj[j] = w;
            sum += w;
        }
#pragma unroll
        for (int off = 32; off; off >>= 1) sum += __shfl_xor(sum, off);

        float o = 0.f;
        for (int j = 0; j < 4; ++j) {
            for (int t2 = 0; t2 < 64; ++t2) {
                int tk = t2 + 64 * j;        // uniform across lanes
                if (tk >= Tk) break;
                float w = __shfl(sj[j], t2);
                o = fmaf(w, Vp[((size_t)b * Tk + tk) * vs + h * 64 + lane], o);
            }
        }
        o /= sum;
        Op[((size_t)b * Tq + tq) * os + h * 64 + lane] = o;
    }
}

// =======================================================================================
extern "C" void kernel_launch(void* const* d_in, const int* in_sizes, int n_in,
                              void* d_out, int out_size, void* d_ws, size_t ws_size,
                              hipStream_t stream) {
    const int D = 768, FF = 3072, NB = 64, S = 196, T = 98, NL = 3;
    const int Menc = NB * S;   // 12544
    const int Mdec = NB * T;   // 6272

    auto IN = [&](int i) { return (const float*)d_in[i]; };
    const float* ctx = IN(0);
    const int* tpos = (const int*)d_in[1];
    const float* spe = IN(2);
    const float* norm_g = IN(3);
    const float* norm_b = IN(4);

    char* base;
    if (ws_size >= ARENA_BYTES) {
        base = (char*)d_ws;
    } else {
        void* sym = nullptr;
        if (hipGetSymbolAddress(&sym, HIP_SYMBOL(g_arena)) == hipSuccess && sym)
            base = (char*)sym;
        else
            base = (char*)d_ws;
    }
    char* pp = base;
    auto alloc = [&](long long bytes) -> void* {
        void* r = (void*)pp;
        pp += (bytes + 255) & ~255LL;
        return r;
    };
    int* flag = (int*)alloc(256);
    int* flagD = flag + 1;                                   // byte offset 4, inside flag slot
    u16* wscr = (u16*)alloc((long long)FF * D * 2);          // bf16 transposed-weight scratch
    float* x = (float*)alloc((long long)Menc * D * 4);       // encoder residual stream
    float* h = (float*)alloc((long long)Menc * D * 4);       // LN out / attn out
    float* s1 = (float*)alloc((long long)Menc * FF * 4);     // qkv / ff1 / dec qq,kk,vv
    float* q = (float*)alloc((long long)Mdec * D * 4);       // decoder residual stream

    hipMemsetAsync(flagD, 0x01, 4, stream);                  // presume int64
    k_detect_i64<<<dim3((Mdec / 2 + 255) / 256), dim3(256), 0, stream>>>(tpos, Mdec / 2, flagD);

    auto wtrans = [&](const float* W, int K, int N) {
        int tot = N * (K / 8);
        k_wtrans<<<dim3((tot + 255) / 256), dim3(256), 0, stream>>>(W, wscr, K, N);
    };
    // mode 0: plain, 1: +residual, 2: gelu
    auto gemm = [&](int mode, const float* A, const float* W, const float* bias,
                    const float* R, float* C, int M, int N, int K) {
        wtrans(W, K, N);
        dim3 g(M / 128, N / 128), blk(256);
        if (mode == 0)      k_gemmM<false, false><<<g, blk, 0, stream>>>(A, wscr, bias, nullptr, C, M, N, K);
        else if (mode == 1) k_gemmM<false, true><<<g, blk, 0, stream>>>(A, wscr, bias, R, C, M, N, K);
        else                k_gemmM<true, false><<<g, blk, 0, stream>>>(A, wscr, bias, nullptr, C, M, N, K);
    };
    auto ln = [&](const float* X, const float* gg, const float* bb, float* Of, int M) {
        k_ln32<<<dim3(M), dim3(256), 0, stream>>>(X, gg, bb, Of);
    };
    auto attn = [&](const float* Q, int qs, const float* Kp, int ks2, const float* Vp, int vs,
                    float* O, int Tq, int Tk) {
        k_attn32<<<dim3(NB * 12), dim3(256), 0, stream>>>(Q, qs, Kp, ks2, Vp, vs, O, D, Tq, Tk);
    };

    // pre-norm transformer block (self-attn + GELU MLP, residuals); Xf updated in place
    auto tblock = [&](float* Xf, int Mtok, int Tseq, int basei, int l) {
        const float* ln1g = IN(basei + 0) + l * D;
        const float* ln1b = IN(basei + 1) + l * D;
        const float* wqkv = IN(basei + 2) + (long long)l * D * 3 * D;
        const float* bqkv = IN(basei + 3) + l * 3 * D;
        const float* wo = IN(basei + 4) + (long long)l * D * D;
        const float* bo = IN(basei + 5) + l * D;
        const float* ln2g = IN(basei + 6) + l * D;
        const float* ln2b = IN(basei + 7) + l * D;
        const float* w1 = IN(basei + 8) + (long long)l * D * FF;
        const float* b1 = IN(basei + 9) + l * FF;
        const float* w2 = IN(basei + 10) + (long long)l * FF * D;
        const float* b2 = IN(basei + 11) + l * D;

        ln(Xf, ln1g, ln1b, h, Mtok);
        gemm(0, h, wqkv, bqkv, nullptr, s1, Mtok, 3 * D, D);              // qkv
        attn(s1, 3 * D, s1 + D, 3 * D, s1 + 2 * D, 3 * D, h, Tseq, Tseq); // self-attn -> h
        gemm(1, h, wo, bo, Xf, Xf, Mtok, D, D);                           // x += ao@wo+bo
        ln(Xf, ln2g, ln2b, h, Mtok);
        gemm(2, h, w1, b1, nullptr, s1, Mtok, FF, D);                     // gelu(h@w1+b1)
        gemm(1, s1, w2, b2, Xf, Xf, Mtok, D, FF);                         // x += ff@w2+b2
    };

    // ---------------- encoder ----------------
    hipMemcpyAsync(x, ctx, (long long)Menc * D * 4, hipMemcpyDeviceToDevice, stream);
    for (int l = 0; l < NL; ++l)
        tblock(x, Menc, S, 5, l);

    // ---------------- decoder ----------------
    k_gather32<<<dim3(Mdec), dim3(256), 0, stream>>>(spe, tpos, flagD, q);
    float* qq = s1;
    float* kk = s1 + (long long)Mdec * D;
    float* vv = kk + (long long)Menc * D;
    for (int l = 0; l < NL; ++l) {
        gemm(0, q, IN(29) + (long long)l * D * D, IN(30) + l * D, nullptr, qq, Mdec, D, D);
        gemm(0, x, IN(31) + (long long)l * D * D, IN(32) + l * D, nullptr, kk, Menc, D, D);
        gemm(0, x, IN(33) + (long long)l * D * D, IN(34) + l * D, nullptr, vv, Menc, D, D);
        attn(qq, D, kk, D, vv, D, h, T, S);                               // cross-attn -> h
        gemm(0, h, IN(35) + (long long)l * D * D, IN(36) + l * D, nullptr, q, Mdec, D, D);
        tblock(q, Mdec, T, 17, l);
    }
    ln(q, norm_g, norm_b, (float*)d_out, Mdec);
}

// Round 8
// 15780.986 us; speedup vs baseline: 7.5259x; 1.3456x over previous
//
#include <hip/hip_runtime.h>

typedef unsigned short u16;
typedef __attribute__((ext_vector_type(8))) __bf16 bf16x8;
typedef __attribute__((ext_vector_type(4))) float f32x4;

#define DEV static __device__ __forceinline__

// fp32 arena + bf16 weight scratch
#define ARENA_BYTES 255197440ULL
__device__ __align__(256) char g_arena[ARENA_BYTES];

DEV float bf2f(u16 u) { return __uint_as_float(((unsigned)u) << 16); }
DEV u16 f2bf(float f) {
    unsigned u = __float_as_uint(f);
    return (u16)((u + 0x7fffu + ((u >> 16) & 1u)) >> 16);
}
DEV float gelu_tanh(float x) {
    float x3 = x * x * x;
    return 0.5f * x * (1.f + tanhf(0.7978845608028654f * (x + 0.044715f * x3)));
}

// ---- target_positions dtype sniff: int64 iff ALL odd int32 slots are 0 ----
__global__ __launch_bounds__(256) void k_detect_i64(const int* __restrict__ pos, int nhalf,
                                                    int* __restrict__ flagD) {
    int i = blockIdx.x * 256 + threadIdx.x;
    if (i < nhalf && pos[2 * i + 1] != 0) atomicAnd(flagD, 0);
}

// ---- gather rows of spatial_pos_embed (dtype-robust, clamped) ----
__global__ __launch_bounds__(256) void k_gather32(const float* __restrict__ spe,
                                                  const int* __restrict__ pos,
                                                  const int* __restrict__ flagD,
                                                  float* __restrict__ qf) {
    int row = blockIdx.x;
    int p = (*flagD) ? pos[2 * row] : pos[row];
    p = (p < 0) ? 0 : (p > 195 ? 195 : p);
    const float* src = spe + (size_t)p * 768;
    size_t o = (size_t)row * 768;
    for (int i = threadIdx.x; i < 768; i += 256) qf[o + i] = src[i];
}

// ---- LayerNorm over 768, fp32 -> fp32, one block per row ----
__global__ __launch_bounds__(256) void k_ln32(const float* __restrict__ X,
                                              const float* __restrict__ g,
                                              const float* __restrict__ b,
                                              float* __restrict__ Of) {
    const int row = blockIdx.x, tid = threadIdx.x;
    const float* xr = X + (size_t)row * 768;
    float v0 = xr[tid], v1 = xr[tid + 256], v2 = xr[tid + 512];
    float s = v0 + v1 + v2, s2 = v0 * v0 + v1 * v1 + v2 * v2;
#pragma unroll
    for (int off = 32; off; off >>= 1) {
        s += __shfl_xor(s, off);
        s2 += __shfl_xor(s2, off);
    }
    __shared__ float red[8];
    const int wid = tid >> 6, lane = tid & 63;
    if (lane == 0) { red[wid] = s; red[4 + wid] = s2; }
    __syncthreads();
    s = red[0] + red[1] + red[2] + red[3];
    s2 = red[4] + red[5] + red[6] + red[7];
    const float mu = s * (1.f / 768.f);
    const float var = fmaxf(s2 * (1.f / 768.f) - mu * mu, 0.f);
    const float rs = rsqrtf(var + 1e-5f);
    size_t o = (size_t)row * 768;
#pragma unroll
    for (int i = 0; i < 3; ++i) {
        int c = tid + 256 * i;
        float vv = (i == 0 ? v0 : (i == 1 ? v1 : v2));
        Of[o + c] = (vv - mu) * rs * g[c] + b[c];
    }
}

// ---- weight transpose + fp32->bf16 convert: W[K,N] -> WT[N,K] ----
__global__ __launch_bounds__(256) void k_wtrans(const float* __restrict__ W,
                                                u16* __restrict__ WT, int K, int N) {
    int idx = blockIdx.x * 256 + threadIdx.x;
    int tot = N * (K >> 3);
    if (idx >= tot) return;
    int n = idx % N;
    int kc = idx / N;
    union { u16 u[8]; int4 v; } tmp;
#pragma unroll
    for (int j = 0; j < 8; ++j) tmp.u[j] = f2bf(W[(size_t)(kc * 8 + j) * N + n]);
    *(int4*)&WT[(size_t)n * K + kc * 8] = tmp.v;
}

// ---- MFMA GEMM, fp32 in / fp32 out: C[M,N] = A32[M,K] @ BT[N,K]^T + bias (+gelu/+res) ----
// 128x128 tile, BK=32, 4 waves (2x2), each wave 64x64 = 4x4 frags of 16x16x32 bf16.
template <bool GELU_, bool RES_>
__global__ __launch_bounds__(256) void k_gemmM(const float* __restrict__ A,
                                               const u16* __restrict__ BT,
                                               const float* __restrict__ bias,
                                               const float* __restrict__ R,
                                               float* __restrict__ C,
                                               int M, int N, int K) {
    __shared__ __align__(16) u16 Asm[128 * 32];
    __shared__ __align__(16) u16 Bsm[128 * 32];
    const int tid = threadIdx.x;
    const int lane = tid & 63;
    const int wid = tid >> 6;
    const int wm = wid >> 1, wn = wid & 1;
    const size_t Abase = (size_t)blockIdx.x * 128 * K;   // float elements
    const size_t Bbase = (size_t)blockIdx.y * 128 * K;   // u16 elements

    f32x4 acc[4][4] = {};
    const int r0 = tid >> 2;
    const int ko0 = (tid & 3) * 8;

    for (int k0 = 0; k0 < K; k0 += 32) {
        const float* Ag0 = A + Abase + (size_t)r0 * K + k0 + ko0;
        const float* Ag1 = Ag0 + (size_t)64 * K;
        {
            float4 a0 = *(const float4*)Ag0, a1 = *(const float4*)(Ag0 + 4);
            union { u16 u[8]; int4 v; } t;
            t.u[0] = f2bf(a0.x); t.u[1] = f2bf(a0.y); t.u[2] = f2bf(a0.z); t.u[3] = f2bf(a0.w);
            t.u[4] = f2bf(a1.x); t.u[5] = f2bf(a1.y); t.u[6] = f2bf(a1.z); t.u[7] = f2bf(a1.w);
            *(int4*)&Asm[tid * 8] = t.v;
        }
        {
            float4 a0 = *(const float4*)Ag1, a1 = *(const float4*)(Ag1 + 4);
            union { u16 u[8]; int4 v; } t;
            t.u[0] = f2bf(a0.x); t.u[1] = f2bf(a0.y); t.u[2] = f2bf(a0.z); t.u[3] = f2bf(a0.w);
            t.u[4] = f2bf(a1.x); t.u[5] = f2bf(a1.y); t.u[6] = f2bf(a1.z); t.u[7] = f2bf(a1.w);
            *(int4*)&Asm[(256 + tid) * 8] = t.v;
        }
        const u16* Bg = BT + Bbase + (size_t)r0 * K + k0 + ko0;
        *(int4*)&Bsm[tid * 8] = *(const int4*)Bg;
        *(int4*)&Bsm[(256 + tid) * 8] = *(const int4*)(Bg + (size_t)64 * K);
        __syncthreads();

        const int fr = lane & 15, g = lane >> 4;
        bf16x8 af[4], bfr[4];
#pragma unroll
        for (int i = 0; i < 4; ++i) {
            af[i] = *(const bf16x8*)&Asm[(wm * 64 + i * 16 + fr) * 32 + g * 8];
            bfr[i] = *(const bf16x8*)&Bsm[(wn * 64 + i * 16 + fr) * 32 + g * 8];
        }
#pragma unroll
        for (int i = 0; i < 4; ++i)
#pragma unroll
            for (int j = 0; j < 4; ++j)
                acc[i][j] = __builtin_amdgcn_mfma_f32_16x16x32_bf16(af[i], bfr[j], acc[i][j], 0, 0, 0);
        __syncthreads();
    }

    // C/D layout: col=lane&15, row=(lane>>4)*4+reg  [HW-verified m89/m91]
    const int fr = lane & 15, g4 = (lane >> 4) * 4;
#pragma unroll
    for (int j = 0; j < 4; ++j) {
        const int col = blockIdx.y * 128 + wn * 64 + j * 16 + fr;
        const float bc = bias[col];
#pragma unroll
        for (int i = 0; i < 4; ++i) {
#pragma unroll
            for (int r = 0; r < 4; ++r) {
                const int row = blockIdx.x * 128 + wm * 64 + i * 16 + g4 + r;
                float v = acc[i][j][r] + bc;
                if (GELU_) v = gelu_tanh(v);
                if (RES_)  v += R[(size_t)row * N + col];
                C[(size_t)row * N + col] = v;
            }
        }
    }
}

// ---- fp32 attention, LDS-staged K/V; math identical to known-good shuffle version ----
// K^T in kt[64][201] (QK read: lanes=tk consecutive, conflict-free);
// V in vl[196][65] (PV read: lanes=d consecutive, 2-way=free). 102.4KB LDS, 1 block/CU.
__global__ __launch_bounds__(256) void k_attnL(const float* __restrict__ Qp, int qs,
                                               const float* __restrict__ Kp, int ks,
                                               const float* __restrict__ Vp, int vs,
                                               float* __restrict__ Op, int os,
                                               int Tq, int Tk) {
    __shared__ float kt[64][201];
    __shared__ float vl[196][65];
    const int bh = blockIdx.x, b = bh / 12, h = bh % 12;
    const int tid = threadIdx.x, lane = tid & 63, wid = tid >> 6;

    // stage: global reads coalesced (lane = d); LDS writes 2-way max
    for (int idx = tid; idx < Tk * 64; idx += 256) {
        int tk = idx >> 6, d = idx & 63;
        size_t ro = (size_t)b * Tk + tk;
        float kvv = Kp[ro * ks + h * 64 + d];
        float vvv = Vp[ro * vs + h * 64 + d];
        kt[d][tk] = kvv;
        vl[tk][d] = vvv;
    }
    __syncthreads();

    for (int tq = wid; tq < Tq; tq += 4) {
        const float qv = Qp[((size_t)b * Tq + tq) * qs + h * 64 + lane];
        float sj[4];
        int tkj[4];
#pragma unroll
        for (int j = 0; j < 4; ++j) {
            sj[j] = 0.f;
            int t_ = lane + 64 * j;
            tkj[j] = (t_ < Tk) ? t_ : 0;
        }
        for (int d = 0; d < 64; ++d) {
            const float qd = __shfl(qv, d);
#pragma unroll
            for (int j = 0; j < 4; ++j)
                sj[j] = fmaf(qd, kt[d][tkj[j]], sj[j]);
        }
        float mx = -1e30f;
#pragma unroll
        for (int j = 0; j < 4; ++j) {
            sj[j] *= 0.125f;                       // 1/sqrt(64)
            if (lane + 64 * j < Tk) mx = fmaxf(mx, sj[j]);
        }
#pragma unroll
        for (int off = 32; off; off >>= 1) mx = fmaxf(mx, __shfl_xor(mx, off));
        float sum = 0.f;
#pragma unroll
        for (int j = 0; j < 4; ++j) {
            float w = (lane + 64 * j < Tk) ? __expf(sj[j] - mx) : 0.f;
            sj[j] = w;
            sum += w;
        }
#pragma unroll
        for (int off = 32; off; off >>= 1) sum += __shfl_xor(sum, off);

        float o = 0.f;
        for (int j = 0; j < 4; ++j) {
            for (int t2 = 0; t2 < 64; ++t2) {
                int tk = t2 + 64 * j;        // uniform across lanes
                if (tk >= Tk) break;
                float w = __shfl(sj[j], t2); // full-wave shuffle before any divergence
                o = fmaf(w, vl[tk][lane], o);
            }
        }
        o /= sum;
        Op[((size_t)b * Tq + tq) * os + h * 64 + lane] = o;
    }
}

// =======================================================================================
extern "C" void kernel_launch(void* const* d_in, const int* in_sizes, int n_in,
                              void* d_out, int out_size, void* d_ws, size_t ws_size,
                              hipStream_t stream) {
    const int D = 768, FF = 3072, NB = 64, S = 196, T = 98, NL = 3;
    const int Menc = NB * S;   // 12544
    const int Mdec = NB * T;   // 6272

    auto IN = [&](int i) { return (const float*)d_in[i]; };
    const float* ctx = IN(0);
    const int* tpos = (const int*)d_in[1];
    const float* spe = IN(2);
    const float* norm_g = IN(3);
    const float* norm_b = IN(4);

    char* base;
    if (ws_size >= ARENA_BYTES) {
        base = (char*)d_ws;
    } else {
        void* sym = nullptr;
        if (hipGetSymbolAddress(&sym, HIP_SYMBOL(g_arena)) == hipSuccess && sym)
            base = (char*)sym;
        else
            base = (char*)d_ws;
    }
    char* pp = base;
    auto alloc = [&](long long bytes) -> void* {
        void* r = (void*)pp;
        pp += (bytes + 255) & ~255LL;
        return r;
    };
    int* flag = (int*)alloc(256);
    int* flagD = flag + 1;                                   // byte offset 4, inside flag slot
    u16* wscr = (u16*)alloc((long long)FF * D * 2);          // bf16 transposed-weight scratch
    float* x = (float*)alloc((long long)Menc * D * 4);       // encoder residual stream
    float* h = (float*)alloc((long long)Menc * D * 4);       // LN out / attn out
    float* s1 = (float*)alloc((long long)Menc * FF * 4);     // qkv / ff1 / dec qq,kk,vv
    float* q = (float*)alloc((long long)Mdec * D * 4);       // decoder residual stream

    hipMemsetAsync(flagD, 0x01, 4, stream);                  // presume int64
    k_detect_i64<<<dim3((Mdec / 2 + 255) / 256), dim3(256), 0, stream>>>(tpos, Mdec / 2, flagD);

    auto wtrans = [&](const float* W, int K, int N) {
        int tot = N * (K / 8);
        k_wtrans<<<dim3((tot + 255) / 256), dim3(256), 0, stream>>>(W, wscr, K, N);
    };
    // mode 0: plain, 1: +residual, 2: gelu
    auto gemm = [&](int mode, const float* A, const float* W, const float* bias,
                    const float* R, float* C, int M, int N, int K) {
        wtrans(W, K, N);
        dim3 g(M / 128, N / 128), blk(256);
        if (mode == 0)      k_gemmM<false, false><<<g, blk, 0, stream>>>(A, wscr, bias, nullptr, C, M, N, K);
        else if (mode == 1) k_gemmM<false, true><<<g, blk, 0, stream>>>(A, wscr, bias, R, C, M, N, K);
        else                k_gemmM<true, false><<<g, blk, 0, stream>>>(A, wscr, bias, nullptr, C, M, N, K);
    };
    auto ln = [&](const float* X, const float* gg, const float* bb, float* Of, int M) {
        k_ln32<<<dim3(M), dim3(256), 0, stream>>>(X, gg, bb, Of);
    };
    auto attn = [&](const float* Q, int qs, const float* Kp, int ks2, const float* Vp, int vs,
                    float* O, int Tq, int Tk) {
        k_attnL<<<dim3(NB * 12), dim3(256), 0, stream>>>(Q, qs, Kp, ks2, Vp, vs, O, D, Tq, Tk);
    };

    // pre-norm transformer block (self-attn + GELU MLP, residuals); Xf updated in place
    auto tblock = [&](float* Xf, int Mtok, int Tseq, int basei, int l) {
        const float* ln1g = IN(basei + 0) + l * D;
        const float* ln1b = IN(basei + 1) + l * D;
        const float* wqkv = IN(basei + 2) + (long long)l * D * 3 * D;
        const float* bqkv = IN(basei + 3) + l * 3 * D;
        const float* wo = IN(basei + 4) + (long long)l * D * D;
        const float* bo = IN(basei + 5) + l * D;
        const float* ln2g = IN(basei + 6) + l * D;
        const float* ln2b = IN(basei + 7) + l * D;
        const float* w1 = IN(basei + 8) + (long long)l * D * FF;
        const float* b1 = IN(basei + 9) + l * FF;
        const float* w2 = IN(basei + 10) + (long long)l * FF * D;
        const float* b2 = IN(basei + 11) + l * D;

        ln(Xf, ln1g, ln1b, h, Mtok);
        gemm(0, h, wqkv, bqkv, nullptr, s1, Mtok, 3 * D, D);              // qkv
        attn(s1, 3 * D, s1 + D, 3 * D, s1 + 2 * D, 3 * D, h, Tseq, Tseq); // self-attn -> h
        gemm(1, h, wo, bo, Xf, Xf, Mtok, D, D);                           // x += ao@wo+bo
        ln(Xf, ln2g, ln2b, h, Mtok);
        gemm(2, h, w1, b1, nullptr, s1, Mtok, FF, D);                     // gelu(h@w1+b1)
        gemm(1, s1, w2, b2, Xf, Xf, Mtok, D, FF);                         // x += ff@w2+b2
    };

    // ---------------- encoder ----------------
    hipMemcpyAsync(x, ctx, (long long)Menc * D * 4, hipMemcpyDeviceToDevice, stream);
    for (int l = 0; l < NL; ++l)
        tblock(x, Menc, S, 5, l);

    // ---------------- decoder ----------------
    k_gather32<<<dim3(Mdec), dim3(256), 0, stream>>>(spe, tpos, flagD, q);
    float* qq = s1;
    float* kk = s1 + (long long)Mdec * D;
    float* vv = kk + (long long)Menc * D;
    for (int l = 0; l < NL; ++l) {
        gemm(0, q, IN(29) + (long long)l * D * D, IN(30) + l * D, nullptr, qq, Mdec, D, D);
        gemm(0, x, IN(31) + (long long)l * D * D, IN(32) + l * D, nullptr, kk, Menc, D, D);
        gemm(0, x, IN(33) + (long long)l * D * D, IN(34) + l * D, nullptr, vv, Menc, D, D);
        attn(qq, D, kk, D, vv, D, h, T, S);                               // cross-attn -> h
        gemm(0, h, IN(35) + (long long)l * D * D, IN(36) + l * D, nullptr, q, Mdec, D, D);
        tblock(q, Mdec, T, 17, l);
    }
    ln(q, norm_g, norm_b, (float*)d_out, Mdec);
}

// Round 9
// 7823.594 us; speedup vs baseline: 15.1806x; 2.0171x over previous
//
#include <hip/hip_runtime.h>

typedef unsigned short u16;
typedef __attribute__((ext_vector_type(8))) __bf16 bf16x8;
typedef __attribute__((ext_vector_type(4))) float f32x4;

#define DEV static __device__ __forceinline__

// fp32 arena + bf16 weight scratch
#define ARENA_BYTES 255197440ULL
__device__ __align__(256) char g_arena[ARENA_BYTES];

DEV float bf2f(u16 u) { return __uint_as_float(((unsigned)u) << 16); }
DEV u16 f2bf(float f) {
    unsigned u = __float_as_uint(f);
    return (u16)((u + 0x7fffu + ((u >> 16) & 1u)) >> 16);
}
DEV float gelu_tanh(float x) {
    float x3 = x * x * x;
    return 0.5f * x * (1.f + tanhf(0.7978845608028654f * (x + 0.044715f * x3)));
}

// ---- target_positions dtype sniff: int64 iff ALL odd int32 slots are 0 ----
__global__ __launch_bounds__(256) void k_detect_i64(const int* __restrict__ pos, int nhalf,
                                                    int* __restrict__ flagD) {
    int i = blockIdx.x * 256 + threadIdx.x;
    if (i < nhalf && pos[2 * i + 1] != 0) atomicAnd(flagD, 0);
}

// ---- gather rows of spatial_pos_embed (dtype-robust, clamped) ----
__global__ __launch_bounds__(256) void k_gather32(const float* __restrict__ spe,
                                                  const int* __restrict__ pos,
                                                  const int* __restrict__ flagD,
                                                  float* __restrict__ qf) {
    int row = blockIdx.x;
    int p = (*flagD) ? pos[2 * row] : pos[row];
    p = (p < 0) ? 0 : (p > 195 ? 195 : p);
    const float* src = spe + (size_t)p * 768;
    size_t o = (size_t)row * 768;
    for (int i = threadIdx.x; i < 768; i += 256) qf[o + i] = src[i];
}

// ---- LayerNorm over 768, fp32 -> fp32, one block per row ----
__global__ __launch_bounds__(256) void k_ln32(const float* __restrict__ X,
                                              const float* __restrict__ g,
                                              const float* __restrict__ b,
                                              float* __restrict__ Of) {
    const int row = blockIdx.x, tid = threadIdx.x;
    const float* xr = X + (size_t)row * 768;
    float v0 = xr[tid], v1 = xr[tid + 256], v2 = xr[tid + 512];
    float s = v0 + v1 + v2, s2 = v0 * v0 + v1 * v1 + v2 * v2;
#pragma unroll
    for (int off = 32; off; off >>= 1) {
        s += __shfl_xor(s, off);
        s2 += __shfl_xor(s2, off);
    }
    __shared__ float red[8];
    const int wid = tid >> 6, lane = tid & 63;
    if (lane == 0) { red[wid] = s; red[4 + wid] = s2; }
    __syncthreads();
    s = red[0] + red[1] + red[2] + red[3];
    s2 = red[4] + red[5] + red[6] + red[7];
    const float mu = s * (1.f / 768.f);
    const float var = fmaxf(s2 * (1.f / 768.f) - mu * mu, 0.f);
    const float rs = rsqrtf(var + 1e-5f);
    size_t o = (size_t)row * 768;
#pragma unroll
    for (int i = 0; i < 3; ++i) {
        int c = tid + 256 * i;
        float vv = (i == 0 ? v0 : (i == 1 ? v1 : v2));
        Of[o + c] = (vv - mu) * rs * g[c] + b[c];
    }
}

// ---- weight transpose + fp32->bf16 convert: W[K,N] -> WT[N,K] ----
__global__ __launch_bounds__(256) void k_wtrans(const float* __restrict__ W,
                                                u16* __restrict__ WT, int K, int N) {
    int idx = blockIdx.x * 256 + threadIdx.x;
    int tot = N * (K >> 3);
    if (idx >= tot) return;
    int n = idx % N;
    int kc = idx / N;
    union { u16 u[8]; int4 v; } tmp;
#pragma unroll
    for (int j = 0; j < 8; ++j) tmp.u[j] = f2bf(W[(size_t)(kc * 8 + j) * N + n]);
    *(int4*)&WT[(size_t)n * K + kc * 8] = tmp.v;
}

// ---- MFMA GEMM, fp32 in / fp32 out: C[M,N] = A32[M,K] @ BT[N,K]^T + bias (+gelu/+res) ----
// 128x128 tile, BK=32, 4 waves (2x2), each wave 64x64 = 4x4 frags of 16x16x32 bf16.
template <bool GELU_, bool RES_>
__global__ __launch_bounds__(256) void k_gemmM(const float* __restrict__ A,
                                               const u16* __restrict__ BT,
                                               const float* __restrict__ bias,
                                               const float* __restrict__ R,
                                               float* __restrict__ C,
                                               int M, int N, int K) {
    __shared__ __align__(16) u16 Asm[128 * 32];
    __shared__ __align__(16) u16 Bsm[128 * 32];
    const int tid = threadIdx.x;
    const int lane = tid & 63;
    const int wid = tid >> 6;
    const int wm = wid >> 1, wn = wid & 1;
    const size_t Abase = (size_t)blockIdx.x * 128 * K;   // float elements
    const size_t Bbase = (size_t)blockIdx.y * 128 * K;   // u16 elements

    f32x4 acc[4][4] = {};
    const int r0 = tid >> 2;
    const int ko0 = (tid & 3) * 8;

    for (int k0 = 0; k0 < K; k0 += 32) {
        const float* Ag0 = A + Abase + (size_t)r0 * K + k0 + ko0;
        const float* Ag1 = Ag0 + (size_t)64 * K;
        {
            float4 a0 = *(const float4*)Ag0, a1 = *(const float4*)(Ag0 + 4);
            union { u16 u[8]; int4 v; } t;
            t.u[0] = f2bf(a0.x); t.u[1] = f2bf(a0.y); t.u[2] = f2bf(a0.z); t.u[3] = f2bf(a0.w);
            t.u[4] = f2bf(a1.x); t.u[5] = f2bf(a1.y); t.u[6] = f2bf(a1.z); t.u[7] = f2bf(a1.w);
            *(int4*)&Asm[tid * 8] = t.v;
        }
        {
            float4 a0 = *(const float4*)Ag1, a1 = *(const float4*)(Ag1 + 4);
            union { u16 u[8]; int4 v; } t;
            t.u[0] = f2bf(a0.x); t.u[1] = f2bf(a0.y); t.u[2] = f2bf(a0.z); t.u[3] = f2bf(a0.w);
            t.u[4] = f2bf(a1.x); t.u[5] = f2bf(a1.y); t.u[6] = f2bf(a1.z); t.u[7] = f2bf(a1.w);
            *(int4*)&Asm[(256 + tid) * 8] = t.v;
        }
        const u16* Bg = BT + Bbase + (size_t)r0 * K + k0 + ko0;
        *(int4*)&Bsm[tid * 8] = *(const int4*)Bg;
        *(int4*)&Bsm[(256 + tid) * 8] = *(const int4*)(Bg + (size_t)64 * K);
        __syncthreads();

        const int fr = lane & 15, g = lane >> 4;
        bf16x8 af[4], bfr[4];
#pragma unroll
        for (int i = 0; i < 4; ++i) {
            af[i] = *(const bf16x8*)&Asm[(wm * 64 + i * 16 + fr) * 32 + g * 8];
            bfr[i] = *(const bf16x8*)&Bsm[(wn * 64 + i * 16 + fr) * 32 + g * 8];
        }
#pragma unroll
        for (int i = 0; i < 4; ++i)
#pragma unroll
            for (int j = 0; j < 4; ++j)
                acc[i][j] = __builtin_amdgcn_mfma_f32_16x16x32_bf16(af[i], bfr[j], acc[i][j], 0, 0, 0);
        __syncthreads();
    }

    // C/D layout: col=lane&15, row=(lane>>4)*4+reg  [HW-verified m89/m91]
    const int fr = lane & 15, g4 = (lane >> 4) * 4;
#pragma unroll
    for (int j = 0; j < 4; ++j) {
        const int col = blockIdx.y * 128 + wn * 64 + j * 16 + fr;
        const float bc = bias[col];
#pragma unroll
        for (int i = 0; i < 4; ++i) {
#pragma unroll
            for (int r = 0; r < 4; ++r) {
                const int row = blockIdx.x * 128 + wm * 64 + i * 16 + g4 + r;
                float v = acc[i][j][r] + bc;
                if (GELU_) v = gelu_tanh(v);
                if (RES_)  v += R[(size_t)row * N + col];
                C[(size_t)row * N + col] = v;
            }
        }
    }
}

// ---- fp32 attention v3: K-only LDS (50.96KB -> 3 blocks/CU), V from global (coalesced),
//      4-row tq-blocking per wave. Math order identical to the passing r7/r8 version. ----
__global__ __launch_bounds__(256) void k_attnK(const float* __restrict__ Qp, int qs,
                                               const float* __restrict__ Kp, int ks,
                                               const float* __restrict__ Vp, int vs,
                                               float* __restrict__ Op, int os,
                                               int Tq, int Tk) {
    __shared__ float kl[196][65];        // stride 65 => lane-stride 65 % 32 = 1: conflict-free
    const int bh = blockIdx.x, b = bh / 12, h = bh % 12;
    const int tid = threadIdx.x, lane = tid & 63, wid = tid >> 6;

    for (int idx = tid; idx < Tk * 64; idx += 256) {
        int tk = idx >> 6, d = idx & 63;
        kl[tk][d] = Kp[((size_t)b * Tk + tk) * ks + h * 64 + d];
    }
    __syncthreads();

    const float* Vb = Vp + (size_t)b * Tk * vs + h * 64 + lane;

    for (int tqb = wid * 4; tqb < Tq; tqb += 16) {
        const int nr = (Tq - tqb < 4) ? (Tq - tqb) : 4;   // wave-uniform
        float qv[4], o[4] = {0.f, 0.f, 0.f, 0.f}, sj[4][4], ssum[4];
        int tkj[4];
#pragma unroll
        for (int i = 0; i < 4; ++i)
            qv[i] = (i < nr) ? Qp[((size_t)b * Tq + tqb + i) * qs + h * 64 + lane] : 0.f;
#pragma unroll
        for (int j = 0; j < 4; ++j) {
            int t_ = lane + 64 * j;
            tkj[j] = (t_ < Tk) ? t_ : 0;
#pragma unroll
            for (int i = 0; i < 4; ++i) sj[i][j] = 0.f;
        }
        // QK^T: one kl read feeds 4 q-rows
        for (int d = 0; d < 64; ++d) {
            float kk[4];
#pragma unroll
            for (int j = 0; j < 4; ++j)
                kk[j] = (64 * j < Tk) ? kl[tkj[j]][d] : 0.f;
#pragma unroll
            for (int i = 0; i < 4; ++i) {
                float qd = __shfl(qv[i], d);
#pragma unroll
                for (int j = 0; j < 4; ++j)
                    if (64 * j < Tk) sj[i][j] = fmaf(qd, kk[j], sj[i][j]);
            }
        }
        // softmax per row (identical reduction order to r7/r8)
#pragma unroll
        for (int i = 0; i < 4; ++i) {
            float mx = -1e30f;
#pragma unroll
            for (int j = 0; j < 4; ++j) {
                sj[i][j] *= 0.125f;                   // 1/sqrt(64)
                if (lane + 64 * j < Tk) mx = fmaxf(mx, sj[i][j]);
            }
#pragma unroll
            for (int off = 32; off; off >>= 1) mx = fmaxf(mx, __shfl_xor(mx, off));
            float sum = 0.f;
#pragma unroll
            for (int j = 0; j < 4; ++j) {
                float w = (lane + 64 * j < Tk) ? __expf(sj[i][j] - mx) : 0.f;
                sj[i][j] = w;
                sum += w;
            }
#pragma unroll
            for (int off = 32; off; off >>= 1) sum += __shfl_xor(sum, off);
            ssum[i] = sum;
        }
        // PV: one coalesced V load feeds 4 rows
#pragma unroll
        for (int j = 0; j < 4; ++j) {
            int lim = Tk - 64 * j;
            if (lim <= 0) break;                      // wave-uniform
            if (lim > 64) lim = 64;
            for (int t2 = 0; t2 < lim; ++t2) {
                float vv = Vb[(size_t)(64 * j + t2) * vs];
#pragma unroll
                for (int i = 0; i < 4; ++i) {
                    float w = __shfl(sj[i][j], t2);
                    o[i] = fmaf(w, vv, o[i]);
                }
            }
        }
#pragma unroll
        for (int i = 0; i < 4; ++i)
            if (i < nr)
                Op[((size_t)b * Tq + tqb + i) * os + h * 64 + lane] = o[i] / ssum[i];
    }
}

// =======================================================================================
extern "C" void kernel_launch(void* const* d_in, const int* in_sizes, int n_in,
                              void* d_out, int out_size, void* d_ws, size_t ws_size,
                              hipStream_t stream) {
    const int D = 768, FF = 3072, NB = 64, S = 196, T = 98, NL = 3;
    const int Menc = NB * S;   // 12544
    const int Mdec = NB * T;   // 6272

    auto IN = [&](int i) { return (const float*)d_in[i]; };
    const float* ctx = IN(0);
    const int* tpos = (const int*)d_in[1];
    const float* spe = IN(2);
    const float* norm_g = IN(3);
    const float* norm_b = IN(4);

    char* base;
    if (ws_size >= ARENA_BYTES) {
        base = (char*)d_ws;
    } else {
        void* sym = nullptr;
        if (hipGetSymbolAddress(&sym, HIP_SYMBOL(g_arena)) == hipSuccess && sym)
            base = (char*)sym;
        else
            base = (char*)d_ws;
    }
    char* pp = base;
    auto alloc = [&](long long bytes) -> void* {
        void* r = (void*)pp;
        pp += (bytes + 255) & ~255LL;
        return r;
    };
    int* flag = (int*)alloc(256);
    int* flagD = flag + 1;                                   // byte offset 4, inside flag slot
    u16* wscr = (u16*)alloc((long long)FF * D * 2);          // bf16 transposed-weight scratch
    float* x = (float*)alloc((long long)Menc * D * 4);       // encoder residual stream
    float* h = (float*)alloc((long long)Menc * D * 4);       // LN out / attn out
    float* s1 = (float*)alloc((long long)Menc * FF * 4);     // qkv / ff1 / dec qq,kk,vv
    float* q = (float*)alloc((long long)Mdec * D * 4);       // decoder residual stream

    hipMemsetAsync(flagD, 0x01, 4, stream);                  // presume int64
    k_detect_i64<<<dim3((Mdec / 2 + 255) / 256), dim3(256), 0, stream>>>(tpos, Mdec / 2, flagD);

    auto wtrans = [&](const float* W, int K, int N) {
        int tot = N * (K / 8);
        k_wtrans<<<dim3((tot + 255) / 256), dim3(256), 0, stream>>>(W, wscr, K, N);
    };
    // mode 0: plain, 1: +residual, 2: gelu
    auto gemm = [&](int mode, const float* A, const float* W, const float* bias,
                    const float* R, float* C, int M, int N, int K) {
        wtrans(W, K, N);
        dim3 g(M / 128, N / 128), blk(256);
        if (mode == 0)      k_gemmM<false, false><<<g, blk, 0, stream>>>(A, wscr, bias, nullptr, C, M, N, K);
        else if (mode == 1) k_gemmM<false, true><<<g, blk, 0, stream>>>(A, wscr, bias, R, C, M, N, K);
        else                k_gemmM<true, false><<<g, blk, 0, stream>>>(A, wscr, bias, nullptr, C, M, N, K);
    };
    auto ln = [&](const float* X, const float* gg, const float* bb, float* Of, int M) {
        k_ln32<<<dim3(M), dim3(256), 0, stream>>>(X, gg, bb, Of);
    };
    auto attn = [&](const float* Q, int qs, const float* Kp, int ks2, const float* Vp, int vs,
                    float* O, int Tq, int Tk) {
        k_attnK<<<dim3(NB * 12), dim3(256), 0, stream>>>(Q, qs, Kp, ks2, Vp, vs, O, D, Tq, Tk);
    };

    // pre-norm transformer block (self-attn + GELU MLP, residuals); Xf updated in place
    auto tblock = [&](float* Xf, int Mtok, int Tseq, int basei, int l) {
        const float* ln1g = IN(basei + 0) + l * D;
        const float* ln1b = IN(basei + 1) + l * D;
        const float* wqkv = IN(basei + 2) + (long long)l * D * 3 * D;
        const float* bqkv = IN(basei + 3) + l * 3 * D;
        const float* wo = IN(basei + 4) + (long long)l * D * D;
        const float* bo = IN(basei + 5) + l * D;
        const float* ln2g = IN(basei + 6) + l * D;
        const float* ln2b = IN(basei + 7) + l * D;
        const float* w1 = IN(basei + 8) + (long long)l * D * FF;
        const float* b1 = IN(basei + 9) + l * FF;
        const float* w2 = IN(basei + 10) + (long long)l * FF * D;
        const float* b2 = IN(basei + 11) + l * D;

        ln(Xf, ln1g, ln1b, h, Mtok);
        gemm(0, h, wqkv, bqkv, nullptr, s1, Mtok, 3 * D, D);              // qkv
        attn(s1, 3 * D, s1 + D, 3 * D, s1 + 2 * D, 3 * D, h, Tseq, Tseq); // self-attn -> h
        gemm(1, h, wo, bo, Xf, Xf, Mtok, D, D);                           // x += ao@wo+bo
        ln(Xf, ln2g, ln2b, h, Mtok);
        gemm(2, h, w1, b1, nullptr, s1, Mtok, FF, D);                     // gelu(h@w1+b1)
        gemm(1, s1, w2, b2, Xf, Xf, Mtok, D, FF);                         // x += ff@w2+b2
    };

    // ---------------- encoder ----------------
    hipMemcpyAsync(x, ctx, (long long)Menc * D * 4, hipMemcpyDeviceToDevice, stream);
    for (int l = 0; l < NL; ++l)
        tblock(x, Menc, S, 5, l);

    // ---------------- decoder ----------------
    k_gather32<<<dim3(Mdec), dim3(256), 0, stream>>>(spe, tpos, flagD, q);
    float* qq = s1;
    float* kk = s1 + (long long)Mdec * D;
    float* vv = kk + (long long)Menc * D;
    for (int l = 0; l < NL; ++l) {
        gemm(0, q, IN(29) + (long long)l * D * D, IN(30) + l * D, nullptr, qq, Mdec, D, D);
        gemm(0, x, IN(31) + (long long)l * D * D, IN(32) + l * D, nullptr, kk, Menc, D, D);
        gemm(0, x, IN(33) + (long long)l * D * D, IN(34) + l * D, nullptr, vv, Menc, D, D);
        attn(qq, D, kk, D, vv, D, h, T, S);                               // cross-attn -> h
        gemm(0, h, IN(35) + (long long)l * D * D, IN(36) + l * D, nullptr, q, Mdec, D, D);
        tblock(q, Mdec, T, 17, l);
    }
    ln(q, norm_g, norm_b, (float*)d_out, Mdec);
}

// Round 10
// 6706.592 us; speedup vs baseline: 17.7089x; 1.1666x over previous
//
#include <hip/hip_runtime.h>

typedef unsigned short u16;
typedef __attribute__((ext_vector_type(8))) __bf16 bf16x8;
typedef __attribute__((ext_vector_type(4))) float f32x4;

#define DEV static __device__ __forceinline__

#define ARENA_BYTES 255197440ULL
__device__ __align__(256) char g_arena[ARENA_BYTES];

DEV float bf2f(u16 u) { return __uint_as_float(((unsigned)u) << 16); }
DEV u16 f2bf(float f) {
    unsigned u = __float_as_uint(f);
    return (u16)((u + 0x7fffu + ((u >> 16) & 1u)) >> 16);
}
DEV float gelu_tanh(float x) {
    float x3 = x * x * x;
    return 0.5f * x * (1.f + tanhf(0.7978845608028654f * (x + 0.044715f * x3)));
}

// ---- target_positions dtype sniff: int64 iff ALL odd int32 slots are 0 ----
__global__ __launch_bounds__(256) void k_detect_i64(const int* __restrict__ pos, int nhalf,
                                                    int* __restrict__ flagD) {
    int i = blockIdx.x * 256 + threadIdx.x;
    if (i < nhalf && pos[2 * i + 1] != 0) atomicAnd(flagD, 0);
}

// ---- gather rows of spatial_pos_embed (dtype-robust, clamped) ----
__global__ __launch_bounds__(256) void k_gather32(const float* __restrict__ spe,
                                                  const int* __restrict__ pos,
                                                  const int* __restrict__ flagD,
                                                  float* __restrict__ qf) {
    int row = blockIdx.x;
    int p = (*flagD) ? pos[2 * row] : pos[row];
    p = (p < 0) ? 0 : (p > 195 ? 195 : p);
    const float* src = spe + (size_t)p * 768;
    size_t o = (size_t)row * 768;
    for (int i = threadIdx.x; i < 768; i += 256) qf[o + i] = src[i];
}

// ---- LayerNorm over 768, fp32 -> fp32, one block per row ----
__global__ __launch_bounds__(256) void k_ln32(const float* __restrict__ X,
                                              const float* __restrict__ g,
                                              const float* __restrict__ b,
                                              float* __restrict__ Of) {
    const int row = blockIdx.x, tid = threadIdx.x;
    const float* xr = X + (size_t)row * 768;
    float v0 = xr[tid], v1 = xr[tid + 256], v2 = xr[tid + 512];
    float s = v0 + v1 + v2, s2 = v0 * v0 + v1 * v1 + v2 * v2;
#pragma unroll
    for (int off = 32; off; off >>= 1) {
        s += __shfl_xor(s, off);
        s2 += __shfl_xor(s2, off);
    }
    __shared__ float red[8];
    const int wid = tid >> 6, lane = tid & 63;
    if (lane == 0) { red[wid] = s; red[4 + wid] = s2; }
    __syncthreads();
    s = red[0] + red[1] + red[2] + red[3];
    s2 = red[4] + red[5] + red[6] + red[7];
    const float mu = s * (1.f / 768.f);
    const float var = fmaxf(s2 * (1.f / 768.f) - mu * mu, 0.f);
    const float rs = rsqrtf(var + 1e-5f);
    size_t o = (size_t)row * 768;
#pragma unroll
    for (int i = 0; i < 3; ++i) {
        int c = tid + 256 * i;
        float vv = (i == 0 ? v0 : (i == 1 ? v1 : v2));
        Of[o + c] = (vv - mu) * rs * g[c] + b[c];
    }
}

// ---- MFMA GEMM with fused weight transpose+convert:
//      C[M,N] = A32[M,K] @ W[K,N] + bias (+gelu/+res), 128x128 tile, BK=32, 4 waves ----
template <bool GELU_, bool RES_>
__global__ __launch_bounds__(256) void k_gemmW(const float* __restrict__ A,
                                               const float* __restrict__ W,
                                               const float* __restrict__ bias,
                                               const float* __restrict__ R,
                                               float* __restrict__ C,
                                               int M, int N, int K) {
    __shared__ __align__(16) u16 Asm[128 * 32];
    __shared__ __align__(16) u16 Bsm[128 * 32];
    const int tid = threadIdx.x;
    const int lane = tid & 63;
    const int wid = tid >> 6;
    const int wm = wid >> 1, wn = wid & 1;
    const size_t Abase = (size_t)blockIdx.x * 128 * K;   // float elements

    f32x4 acc[4][4] = {};
    const int r0 = tid >> 2;             // A staging row
    const int ko0 = (tid & 3) * 8;       // A staging k-offset
    const int bn = tid & 127;            // B staging: n within tile
    const int bko = (tid >> 7) * 8;      // B staging: k-offset 0 or 8
    const int gn = blockIdx.y * 128 + bn;

    for (int k0 = 0; k0 < K; k0 += 32) {
        // A: load 8 fp32, convert, 16B LDS store (rows r0 and r0+64) [proven r7-r9]
        const float* Ag0 = A + Abase + (size_t)r0 * K + k0 + ko0;
        const float* Ag1 = Ag0 + (size_t)64 * K;
        {
            float4 a0 = *(const float4*)Ag0, a1 = *(const float4*)(Ag0 + 4);
            union { u16 u[8]; int4 v; } t;
            t.u[0] = f2bf(a0.x); t.u[1] = f2bf(a0.y); t.u[2] = f2bf(a0.z); t.u[3] = f2bf(a0.w);
            t.u[4] = f2bf(a1.x); t.u[5] = f2bf(a1.y); t.u[6] = f2bf(a1.z); t.u[7] = f2bf(a1.w);
            *(int4*)&Asm[tid * 8] = t.v;
        }
        {
            float4 a0 = *(const float4*)Ag1, a1 = *(const float4*)(Ag1 + 4);
            union { u16 u[8]; int4 v; } t;
            t.u[0] = f2bf(a0.x); t.u[1] = f2bf(a0.y); t.u[2] = f2bf(a0.z); t.u[3] = f2bf(a0.w);
            t.u[4] = f2bf(a1.x); t.u[5] = f2bf(a1.y); t.u[6] = f2bf(a1.z); t.u[7] = f2bf(a1.w);
            *(int4*)&Asm[(256 + tid) * 8] = t.v;
        }
        // B: fused transpose+convert from W[K,N] (k_wtrans's coalesced read pattern)
#pragma unroll
        for (int ks2 = 0; ks2 < 32; ks2 += 16) {
            union { u16 u[8]; int4 v; } t;
#pragma unroll
            for (int j = 0; j < 8; ++j)
                t.u[j] = f2bf(W[(size_t)(k0 + bko + ks2 + j) * N + gn]);
            *(int4*)&Bsm[bn * 32 + bko + ks2] = t.v;
        }
        __syncthreads();

        const int fr = lane & 15, g = lane >> 4;
        bf16x8 af[4], bfr[4];
#pragma unroll
        for (int i = 0; i < 4; ++i) {
            af[i] = *(const bf16x8*)&Asm[(wm * 64 + i * 16 + fr) * 32 + g * 8];
            bfr[i] = *(const bf16x8*)&Bsm[(wn * 64 + i * 16 + fr) * 32 + g * 8];
        }
#pragma unroll
        for (int i = 0; i < 4; ++i)
#pragma unroll
            for (int j = 0; j < 4; ++j)
                acc[i][j] = __builtin_amdgcn_mfma_f32_16x16x32_bf16(af[i], bfr[j], acc[i][j], 0, 0, 0);
        __syncthreads();
    }

    // C/D layout: col=lane&15, row=(lane>>4)*4+reg  [HW-verified m89/m91]
    const int fr = lane & 15, g4 = (lane >> 4) * 4;
#pragma unroll
    for (int j = 0; j < 4; ++j) {
        const int col = blockIdx.y * 128 + wn * 64 + j * 16 + fr;
        const float bc = bias[col];
#pragma unroll
        for (int i = 0; i < 4; ++i) {
#pragma unroll
            for (int r = 0; r < 4; ++r) {
                const int row = blockIdx.x * 128 + wm * 64 + i * 16 + g4 + r;
                float v = acc[i][j][r] + bc;
                if (GELU_) v = gelu_tanh(v);
                if (RES_)  v += R[(size_t)row * N + col];
                C[(size_t)row * N + col] = v;
            }
        }
    }
}

// ---- attention v4: K and V both bf16 in LDS (53.3KB -> 3 blocks/CU),
//      fp32 Q via shuffle broadcast, fp32 softmax (orders identical to r9). ----
__global__ __launch_bounds__(256) void k_attnB(const float* __restrict__ Qp, int qs,
                                               const float* __restrict__ Kp, int ks,
                                               const float* __restrict__ Vp, int vs,
                                               float* __restrict__ Op, int os,
                                               int Tq, int Tk) {
    __shared__ u16 kl[196][68];
    __shared__ u16 vl[196][68];
    const int bh = blockIdx.x, b = bh / 12, h = bh % 12;
    const int tid = threadIdx.x, lane = tid & 63, wid = tid >> 6;

    for (int idx = tid; idx < Tk * 64; idx += 256) {
        int tk = idx >> 6, d = idx & 63;
        size_t ro = (size_t)b * Tk + tk;
        kl[tk][d] = f2bf(Kp[ro * ks + h * 64 + d]);
        vl[tk][d] = f2bf(Vp[ro * vs + h * 64 + d]);
    }
    __syncthreads();

    for (int tqb = wid * 4; tqb < Tq; tqb += 16) {
        const int nr = (Tq - tqb < 4) ? (Tq - tqb) : 4;   // wave-uniform
        float qv[4], o[4] = {0.f, 0.f, 0.f, 0.f}, sj[4][4], ssum[4];
        int tkj[4];
#pragma unroll
        for (int i = 0; i < 4; ++i)
            qv[i] = (i < nr) ? Qp[((size_t)b * Tq + tqb + i) * qs + h * 64 + lane] : 0.f;
#pragma unroll
        for (int j = 0; j < 4; ++j) {
            int t_ = lane + 64 * j;
            tkj[j] = (t_ < Tk) ? t_ : 0;
#pragma unroll
            for (int i = 0; i < 4; ++i) sj[i][j] = 0.f;
        }
        // QK^T: paired bf16 K reads; one read feeds 4 q-rows
        for (int d = 0; d < 64; d += 2) {
            float k0[4], k1[4];
#pragma unroll
            for (int j = 0; j < 4; ++j) {
                unsigned kp = (64 * j < Tk) ? *(const unsigned*)&kl[tkj[j]][d] : 0u;
                k0[j] = bf2f((u16)kp);
                k1[j] = bf2f((u16)(kp >> 16));
            }
#pragma unroll
            for (int i = 0; i < 4; ++i) {
                float qd0 = __shfl(qv[i], d);
                float qd1 = __shfl(qv[i], d + 1);
#pragma unroll
                for (int j = 0; j < 4; ++j)
                    if (64 * j < Tk) {
                        sj[i][j] = fmaf(qd0, k0[j], sj[i][j]);
                        sj[i][j] = fmaf(qd1, k1[j], sj[i][j]);
                    }
            }
        }
        // softmax per row (identical reduction order to r9)
#pragma unroll
        for (int i = 0; i < 4; ++i) {
            float mx = -1e30f;
#pragma unroll
            for (int j = 0; j < 4; ++j) {
                sj[i][j] *= 0.125f;                   // 1/sqrt(64)
                if (lane + 64 * j < Tk) mx = fmaxf(mx, sj[i][j]);
            }
#pragma unroll
            for (int off = 32; off; off >>= 1) mx = fmaxf(mx, __shfl_xor(mx, off));
            float sum = 0.f;
#pragma unroll
            for (int j = 0; j < 4; ++j) {
                float w = (lane + 64 * j < Tk) ? __expf(sj[i][j] - mx) : 0.f;
                sj[i][j] = w;
                sum += w;
            }
#pragma unroll
            for (int off = 32; off; off >>= 1) sum += __shfl_xor(sum, off);
            ssum[i] = sum;
        }
        // PV: V from LDS (r8's proven vl[tk][lane] indexing, bf16)
#pragma unroll
        for (int j = 0; j < 4; ++j) {
            int lim = Tk - 64 * j;
            if (lim <= 0) break;                      // wave-uniform
            if (lim > 64) lim = 64;
            for (int t2 = 0; t2 < lim; ++t2) {
                float vv = bf2f(vl[64 * j + t2][lane]);
#pragma unroll
                for (int i = 0; i < 4; ++i) {
                    float w = __shfl(sj[i][j], t2);
                    o[i] = fmaf(w, vv, o[i]);
                }
            }
        }
#pragma unroll
        for (int i = 0; i < 4; ++i)
            if (i < nr)
                Op[((size_t)b * Tq + tqb + i) * os + h * 64 + lane] = o[i] / ssum[i];
    }
}

// =======================================================================================
extern "C" void kernel_launch(void* const* d_in, const int* in_sizes, int n_in,
                              void* d_out, int out_size, void* d_ws, size_t ws_size,
                              hipStream_t stream) {
    const int D = 768, FF = 3072, NB = 64, S = 196, T = 98, NL = 3;
    const int Menc = NB * S;   // 12544
    const int Mdec = NB * T;   // 6272

    auto IN = [&](int i) { return (const float*)d_in[i]; };
    const float* ctx = IN(0);
    const int* tpos = (const int*)d_in[1];
    const float* spe = IN(2);
    const float* norm_g = IN(3);
    const float* norm_b = IN(4);

    char* base;
    if (ws_size >= ARENA_BYTES) {
        base = (char*)d_ws;
    } else {
        void* sym = nullptr;
        if (hipGetSymbolAddress(&sym, HIP_SYMBOL(g_arena)) == hipSuccess && sym)
            base = (char*)sym;
        else
            base = (char*)d_ws;
    }
    char* pp = base;
    auto alloc = [&](long long bytes) -> void* {
        void* r = (void*)pp;
        pp += (bytes + 255) & ~255LL;
        return r;
    };
    int* flag = (int*)alloc(256);
    int* flagD = flag + 1;                                   // byte offset 4, inside flag slot
    float* x = (float*)alloc((long long)Menc * D * 4);       // encoder residual stream
    float* h = (float*)alloc((long long)Menc * D * 4);       // LN out / attn out
    float* s1 = (float*)alloc((long long)Menc * FF * 4);     // qkv / ff1 / dec qq,kk,vv
    float* q = (float*)alloc((long long)Mdec * D * 4);       // decoder residual stream

    hipMemsetAsync(flagD, 0x01, 4, stream);                  // presume int64
    k_detect_i64<<<dim3((Mdec / 2 + 255) / 256), dim3(256), 0, stream>>>(tpos, Mdec / 2, flagD);

    // mode 0: plain, 1: +residual, 2: gelu   (weight transpose fused into GEMM)
    auto gemm = [&](int mode, const float* A, const float* W, const float* bias,
                    const float* R, float* C, int M, int N, int K) {
        dim3 g(M / 128, N / 128), blk(256);
        if (mode == 0)      k_gemmW<false, false><<<g, blk, 0, stream>>>(A, W, bias, nullptr, C, M, N, K);
        else if (mode == 1) k_gemmW<false, true><<<g, blk, 0, stream>>>(A, W, bias, R, C, M, N, K);
        else                k_gemmW<true, false><<<g, blk, 0, stream>>>(A, W, bias, nullptr, C, M, N, K);
    };
    auto ln = [&](const float* X, const float* gg, const float* bb, float* Of, int M) {
        k_ln32<<<dim3(M), dim3(256), 0, stream>>>(X, gg, bb, Of);
    };
    auto attn = [&](const float* Q, int qs, const float* Kp, int ks2, const float* Vp, int vs,
                    float* O, int Tq, int Tk) {
        k_attnB<<<dim3(NB * 12), dim3(256), 0, stream>>>(Q, qs, Kp, ks2, Vp, vs, O, D, Tq, Tk);
    };

    // pre-norm transformer block (self-attn + GELU MLP, residuals); Xf updated in place
    auto tblock = [&](float* Xf, int Mtok, int Tseq, int basei, int l) {
        const float* ln1g = IN(basei + 0) + l * D;
        const float* ln1b = IN(basei + 1) + l * D;
        const float* wqkv = IN(basei + 2) + (long long)l * D * 3 * D;
        const float* bqkv = IN(basei + 3) + l * 3 * D;
        const float* wo = IN(basei + 4) + (long long)l * D * D;
        const float* bo = IN(basei + 5) + l * D;
        const float* ln2g = IN(basei + 6) + l * D;
        const float* ln2b = IN(basei + 7) + l * D;
        const float* w1 = IN(basei + 8) + (long long)l * D * FF;
        const float* b1 = IN(basei + 9) + l * FF;
        const float* w2 = IN(basei + 10) + (long long)l * FF * D;
        const float* b2 = IN(basei + 11) + l * D;

        ln(Xf, ln1g, ln1b, h, Mtok);
        gemm(0, h, wqkv, bqkv, nullptr, s1, Mtok, 3 * D, D);              // qkv
        attn(s1, 3 * D, s1 + D, 3 * D, s1 + 2 * D, 3 * D, h, Tseq, Tseq); // self-attn -> h
        gemm(1, h, wo, bo, Xf, Xf, Mtok, D, D);                           // x += ao@wo+bo
        ln(Xf, ln2g, ln2b, h, Mtok);
        gemm(2, h, w1, b1, nullptr, s1, Mtok, FF, D);                     // gelu(h@w1+b1)
        gemm(1, s1, w2, b2, Xf, Xf, Mtok, D, FF);                         // x += ff@w2+b2
    };

    // ---------------- encoder ----------------
    hipMemcpyAsync(x, ctx, (long long)Menc * D * 4, hipMemcpyDeviceToDevice, stream);
    for (int l = 0; l < NL; ++l)
        tblock(x, Menc, S, 5, l);

    // ---------------- decoder ----------------
    k_gather32<<<dim3(Mdec), dim3(256), 0, stream>>>(spe, tpos, flagD, q);
    float* qq = s1;
    float* kk = s1 + (long long)Mdec * D;
    float* vv = kk + (long long)Menc * D;
    for (int l = 0; l < NL; ++l) {
        gemm(0, q, IN(29) + (long long)l * D * D, IN(30) + l * D, nullptr, qq, Mdec, D, D);
        gemm(0, x, IN(31) + (long long)l * D * D, IN(32) + l * D, nullptr, kk, Menc, D, D);
        gemm(0, x, IN(33) + (long long)l * D * D, IN(34) + l * D, nullptr, vv, Menc, D, D);
        attn(qq, D, kk, D, vv, D, h, T, S);                               // cross-attn -> h
        gemm(0, h, IN(35) + (long long)l * D * D, IN(36) + l * D, nullptr, q, Mdec, D, D);
        tblock(q, Mdec, T, 17, l);
    }
    ln(q, norm_g, norm_b, (float*)d_out, Mdec);
}

// Round 11
// 4516.134 us; speedup vs baseline: 26.2983x; 1.4850x over previous
//
#include <hip/hip_runtime.h>

typedef unsigned short u16;
typedef __attribute__((ext_vector_type(8))) __bf16 bf16x8;
typedef __attribute__((ext_vector_type(4))) float f32x4;

#define DEV static __device__ __forceinline__

#define ARENA_BYTES 255197440ULL
__device__ __align__(256) char g_arena[ARENA_BYTES];

DEV float bf2f(u16 u) { return __uint_as_float(((unsigned)u) << 16); }
DEV u16 f2bf(float f) {
    unsigned u = __float_as_uint(f);
    return (u16)((u + 0x7fffu + ((u >> 16) & 1u)) >> 16);
}
DEV float gelu_tanh(float x) {
    float x3 = x * x * x;
    return 0.5f * x * (1.f + tanhf(0.7978845608028654f * (x + 0.044715f * x3)));
}

// ---- target_positions dtype sniff ----
__global__ __launch_bounds__(256) void k_detect_i64(const int* __restrict__ pos, int nhalf,
                                                    int* __restrict__ flagD) {
    int i = blockIdx.x * 256 + threadIdx.x;
    if (i < nhalf && pos[2 * i + 1] != 0) atomicAnd(flagD, 0);
}

// ---- gather rows of spatial_pos_embed ----
__global__ __launch_bounds__(256) void k_gather32(const float* __restrict__ spe,
                                                  const int* __restrict__ pos,
                                                  const int* __restrict__ flagD,
                                                  float* __restrict__ qf) {
    int row = blockIdx.x;
    int p = (*flagD) ? pos[2 * row] : pos[row];
    p = (p < 0) ? 0 : (p > 195 ? 195 : p);
    const float* src = spe + (size_t)p * 768;
    size_t o = (size_t)row * 768;
    for (int i = threadIdx.x; i < 768; i += 256) qf[o + i] = src[i];
}

// ---- LayerNorm over 768 ----
__global__ __launch_bounds__(256) void k_ln32(const float* __restrict__ X,
                                              const float* __restrict__ g,
                                              const float* __restrict__ b,
                                              float* __restrict__ Of) {
    const int row = blockIdx.x, tid = threadIdx.x;
    const float* xr = X + (size_t)row * 768;
    float v0 = xr[tid], v1 = xr[tid + 256], v2 = xr[tid + 512];
    float s = v0 + v1 + v2, s2 = v0 * v0 + v1 * v1 + v2 * v2;
#pragma unroll
    for (int off = 32; off; off >>= 1) {
        s += __shfl_xor(s, off);
        s2 += __shfl_xor(s2, off);
    }
    __shared__ float red[8];
    const int wid = tid >> 6, lane = tid & 63;
    if (lane == 0) { red[wid] = s; red[4 + wid] = s2; }
    __syncthreads();
    s = red[0] + red[1] + red[2] + red[3];
    s2 = red[4] + red[5] + red[6] + red[7];
    const float mu = s * (1.f / 768.f);
    const float var = fmaxf(s2 * (1.f / 768.f) - mu * mu, 0.f);
    const float rs = rsqrtf(var + 1e-5f);
    size_t o = (size_t)row * 768;
#pragma unroll
    for (int i = 0; i < 3; ++i) {
        int c = tid + 256 * i;
        float vv = (i == 0 ? v0 : (i == 1 ? v1 : v2));
        Of[o + c] = (vv - mu) * rs * g[c] + b[c];
    }
}

// ---- MFMA GEMM with fused weight transpose+convert (unchanged, proven r10) ----
template <bool GELU_, bool RES_>
__global__ __launch_bounds__(256) void k_gemmW(const float* __restrict__ A,
                                               const float* __restrict__ W,
                                               const float* __restrict__ bias,
                                               const float* __restrict__ R,
                                               float* __restrict__ C,
                                               int M, int N, int K) {
    __shared__ __align__(16) u16 Asm[128 * 32];
    __shared__ __align__(16) u16 Bsm[128 * 32];
    const int tid = threadIdx.x;
    const int lane = tid & 63;
    const int wid = tid >> 6;
    const int wm = wid >> 1, wn = wid & 1;
    const size_t Abase = (size_t)blockIdx.x * 128 * K;

    f32x4 acc[4][4] = {};
    const int r0 = tid >> 2;
    const int ko0 = (tid & 3) * 8;
    const int bn = tid & 127;
    const int bko = (tid >> 7) * 8;
    const int gn = blockIdx.y * 128 + bn;

    for (int k0 = 0; k0 < K; k0 += 32) {
        const float* Ag0 = A + Abase + (size_t)r0 * K + k0 + ko0;
        const float* Ag1 = Ag0 + (size_t)64 * K;
        {
            float4 a0 = *(const float4*)Ag0, a1 = *(const float4*)(Ag0 + 4);
            union { u16 u[8]; int4 v; } t;
            t.u[0] = f2bf(a0.x); t.u[1] = f2bf(a0.y); t.u[2] = f2bf(a0.z); t.u[3] = f2bf(a0.w);
            t.u[4] = f2bf(a1.x); t.u[5] = f2bf(a1.y); t.u[6] = f2bf(a1.z); t.u[7] = f2bf(a1.w);
            *(int4*)&Asm[tid * 8] = t.v;
        }
        {
            float4 a0 = *(const float4*)Ag1, a1 = *(const float4*)(Ag1 + 4);
            union { u16 u[8]; int4 v; } t;
            t.u[0] = f2bf(a0.x); t.u[1] = f2bf(a0.y); t.u[2] = f2bf(a0.z); t.u[3] = f2bf(a0.w);
            t.u[4] = f2bf(a1.x); t.u[5] = f2bf(a1.y); t.u[6] = f2bf(a1.z); t.u[7] = f2bf(a1.w);
            *(int4*)&Asm[(256 + tid) * 8] = t.v;
        }
#pragma unroll
        for (int ks2 = 0; ks2 < 32; ks2 += 16) {
            union { u16 u[8]; int4 v; } t;
#pragma unroll
            for (int j = 0; j < 8; ++j)
                t.u[j] = f2bf(W[(size_t)(k0 + bko + ks2 + j) * N + gn]);
            *(int4*)&Bsm[bn * 32 + bko + ks2] = t.v;
        }
        __syncthreads();

        const int fr = lane & 15, g = lane >> 4;
        bf16x8 af[4], bfr[4];
#pragma unroll
        for (int i = 0; i < 4; ++i) {
            af[i] = *(const bf16x8*)&Asm[(wm * 64 + i * 16 + fr) * 32 + g * 8];
            bfr[i] = *(const bf16x8*)&Bsm[(wn * 64 + i * 16 + fr) * 32 + g * 8];
        }
#pragma unroll
        for (int i = 0; i < 4; ++i)
#pragma unroll
            for (int j = 0; j < 4; ++j)
                acc[i][j] = __builtin_amdgcn_mfma_f32_16x16x32_bf16(af[i], bfr[j], acc[i][j], 0, 0, 0);
        __syncthreads();
    }

    const int fr = lane & 15, g4 = (lane >> 4) * 4;
#pragma unroll
    for (int j = 0; j < 4; ++j) {
        const int col = blockIdx.y * 128 + wn * 64 + j * 16 + fr;
        const float bc = bias[col];
#pragma unroll
        for (int i = 0; i < 4; ++i) {
#pragma unroll
            for (int r = 0; r < 4; ++r) {
                const int row = blockIdx.x * 128 + wm * 64 + i * 16 + g4 + r;
                float v = acc[i][j][r] + bc;
                if (GELU_) v = gelu_tanh(v);
                if (RES_)  v += R[(size_t)row * N + col];
                C[(size_t)row * N + col] = v;
            }
        }
    }
}

// ---- load 8 consecutive fp32 -> bf16x8 ----
DEV bf16x8 ldq8(const float* p) {
    float4 a = *(const float4*)p, b = *(const float4*)(p + 4);
    union { u16 u[8]; bf16x8 v; } t;
    t.u[0] = f2bf(a.x); t.u[1] = f2bf(a.y); t.u[2] = f2bf(a.z); t.u[3] = f2bf(a.w);
    t.u[4] = f2bf(b.x); t.u[5] = f2bf(b.y); t.u[6] = f2bf(b.z); t.u[7] = f2bf(b.w);
    return t.v;
}

// ---- MFMA flash attention: one block per (b,h), 4 independent waves.
// kl[208][72]  : K bf16  (QK B-operand BT[tk][d]), rows >= Tk zeroed
// vt[64][272]  : V^T bf16 (PV B-operand BT[d][tk]), cols >= Tk zeroed
// pl[w][16][72]: per-wave P tile bf16 (written via C/D layout, read via A layout)
// Frag layouts HW-verified via the passing GEMM (m89/m91 pattern).
__global__ __launch_bounds__(256) void k_attnM(const float* __restrict__ Qp, int qs,
                                               const float* __restrict__ Kp, int ks,
                                               const float* __restrict__ Vp, int vs,
                                               float* __restrict__ Op, int os,
                                               int Tq, int Tk) {
    __shared__ u16 kl[208][72];
    __shared__ u16 vt[64][272];
    __shared__ u16 pl[4][16][72];
    const int bh = blockIdx.x, b = bh / 12, h = bh % 12;
    const int tid = threadIdx.x, lane = tid & 63, wid = tid >> 6;
    const int fr = lane & 15, g = lane >> 4, g4 = g * 4;

    const int Tkp = (Tk + 15) & ~15;           // padded to 16
    const int NC = (Tkp + 63) >> 6;            // 64-wide tk chunks
    const int TC = NC << 6;

    // stage K (rows Tkp, zero-padded) and V^T (cols TC, zero-padded)
    for (int r = wid; r < Tkp; r += 4) {
        float kv = (r < Tk) ? Kp[((size_t)b * Tk + r) * ks + h * 64 + lane] : 0.f;
        kl[r][lane] = f2bf(kv);
    }
    for (int t = wid; t < TC; t += 4) {
        float vv = (t < Tk) ? Vp[((size_t)b * Tk + t) * vs + h * 64 + lane] : 0.f;
        vt[lane][t] = f2bf(vv);
    }
    __syncthreads();

    const int NT = (Tq + 63) >> 6;
    for (int it = 0; it < NT; ++it) {
        const int qb = (it << 6) + (wid << 4);     // wave-uniform
        if (qb >= Tq) continue;                    // no barriers below: safe

        int qr = qb + fr;
        if (qr >= Tq) qr = 0;                      // finite dummy row; writes guarded
        const float* Qrow = Qp + ((size_t)b * Tq + qr) * qs + h * 64;
        bf16x8 afq0 = ldq8(Qrow + g * 8);
        bf16x8 afq1 = ldq8(Qrow + 32 + g * 8);

        f32x4 acc_o[4] = {};
        float m_r[4] = {-1e30f, -1e30f, -1e30f, -1e30f};
        float lp[4] = {0.f, 0.f, 0.f, 0.f};

        for (int c = 0; c < NC; ++c) {
            const int tk0 = c << 6;
            int NF = (Tkp - tk0) >> 4;
            if (NF > 4) NF = 4;

            // QK^T: S-chunk = Q(16xd64) @ K^T -> acc_s[nf], D-layout rows=q cols=tk
            f32x4 acc_s[4] = {};
#pragma unroll
            for (int nf = 0; nf < 4; ++nf) {
                if (nf < NF) {
                    const u16* kr = &kl[tk0 + nf * 16 + fr][0];
                    acc_s[nf] = __builtin_amdgcn_mfma_f32_16x16x32_bf16(
                        afq0, *(const bf16x8*)&kr[g * 8], acc_s[nf], 0, 0, 0);
                    acc_s[nf] = __builtin_amdgcn_mfma_f32_16x16x32_bf16(
                        afq1, *(const bf16x8*)&kr[32 + g * 8], acc_s[nf], 0, 0, 0);
                }
            }
            // online softmax update (rows = g4+r, cols across fr-group)
            float pm[4] = {-1e30f, -1e30f, -1e30f, -1e30f};
#pragma unroll
            for (int nf = 0; nf < 4; ++nf) {
                if (nf < NF) {
                    const bool cv = (tk0 + nf * 16 + fr) < Tk;
#pragma unroll
                    for (int r = 0; r < 4; ++r) {
                        float sv = acc_s[nf][r] * 0.125f;   // 1/sqrt(64)
                        acc_s[nf][r] = sv;
                        if (cv) pm[r] = fmaxf(pm[r], sv);
                    }
                }
            }
#pragma unroll
            for (int off = 1; off < 16; off <<= 1)
#pragma unroll
                for (int r = 0; r < 4; ++r) pm[r] = fmaxf(pm[r], __shfl_xor(pm[r], off));
            float al[4];
#pragma unroll
            for (int r = 0; r < 4; ++r) {
                float mn = fmaxf(m_r[r], pm[r]);
                al[r] = __expf(m_r[r] - mn);
                m_r[r] = mn;
                lp[r] *= al[r];
            }
#pragma unroll
            for (int nfd = 0; nfd < 4; ++nfd)
#pragma unroll
                for (int r = 0; r < 4; ++r) acc_o[nfd][r] *= al[r];
            // P = exp(S - m), masked; write via C/D layout
#pragma unroll
            for (int nf = 0; nf < 4; ++nf) {
                const bool cv = (nf < NF) && ((tk0 + nf * 16 + fr) < Tk);
#pragma unroll
                for (int r = 0; r < 4; ++r) {
                    float w = cv ? __expf(acc_s[nf][r] - m_r[r]) : 0.f;
                    lp[r] += w;
                    pl[wid][g4 + r][nf * 16 + fr] = f2bf(w);
                }
            }
            // PV: O += P(16x64) @ V-chunk ; P read via A layout, vt via BT layout
#pragma unroll
            for (int ksp = 0; ksp < 2; ++ksp) {
                bf16x8 ap = *(const bf16x8*)&pl[wid][fr][ksp * 32 + g * 8];
#pragma unroll
                for (int nfd = 0; nfd < 4; ++nfd)
                    acc_o[nfd] = __builtin_amdgcn_mfma_f32_16x16x32_bf16(
                        ap, *(const bf16x8*)&vt[nfd * 16 + fr][tk0 + ksp * 32 + g * 8],
                        acc_o[nfd], 0, 0, 0);
            }
        }
        // finalize: row-sum across fr-group, divide, write
#pragma unroll
        for (int off = 1; off < 16; off <<= 1)
#pragma unroll
            for (int r = 0; r < 4; ++r) lp[r] += __shfl_xor(lp[r], off);
#pragma unroll
        for (int r = 0; r < 4; ++r) {
            int qrow = qb + g4 + r;
            if (qrow < Tq) {
                float inv = 1.f / lp[r];
#pragma unroll
                for (int nfd = 0; nfd < 4; ++nfd)
                    Op[((size_t)b * Tq + qrow) * os + h * 64 + nfd * 16 + fr] =
                        acc_o[nfd][r] * inv;
            }
        }
    }
}

// =======================================================================================
extern "C" void kernel_launch(void* const* d_in, const int* in_sizes, int n_in,
                              void* d_out, int out_size, void* d_ws, size_t ws_size,
                              hipStream_t stream) {
    const int D = 768, FF = 3072, NB = 64, S = 196, T = 98, NL = 3;
    const int Menc = NB * S;   // 12544
    const int Mdec = NB * T;   // 6272

    auto IN = [&](int i) { return (const float*)d_in[i]; };
    const float* ctx = IN(0);
    const int* tpos = (const int*)d_in[1];
    const float* spe = IN(2);
    const float* norm_g = IN(3);
    const float* norm_b = IN(4);

    char* base;
    if (ws_size >= ARENA_BYTES) {
        base = (char*)d_ws;
    } else {
        void* sym = nullptr;
        if (hipGetSymbolAddress(&sym, HIP_SYMBOL(g_arena)) == hipSuccess && sym)
            base = (char*)sym;
        else
            base = (char*)d_ws;
    }
    char* pp = base;
    auto alloc = [&](long long bytes) -> void* {
        void* r = (void*)pp;
        pp += (bytes + 255) & ~255LL;
        return r;
    };
    int* flag = (int*)alloc(256);
    int* flagD = flag + 1;
    float* x = (float*)alloc((long long)Menc * D * 4);
    float* h = (float*)alloc((long long)Menc * D * 4);
    float* s1 = (float*)alloc((long long)Menc * FF * 4);
    float* q = (float*)alloc((long long)Mdec * D * 4);

    hipMemsetAsync(flagD, 0x01, 4, stream);
    k_detect_i64<<<dim3((Mdec / 2 + 255) / 256), dim3(256), 0, stream>>>(tpos, Mdec / 2, flagD);

    auto gemm = [&](int mode, const float* A, const float* W, const float* bias,
                    const float* R, float* C, int M, int N, int K) {
        dim3 g(M / 128, N / 128), blk(256);
        if (mode == 0)      k_gemmW<false, false><<<g, blk, 0, stream>>>(A, W, bias, nullptr, C, M, N, K);
        else if (mode == 1) k_gemmW<false, true><<<g, blk, 0, stream>>>(A, W, bias, R, C, M, N, K);
        else                k_gemmW<true, false><<<g, blk, 0, stream>>>(A, W, bias, nullptr, C, M, N, K);
    };
    auto ln = [&](const float* X, const float* gg, const float* bb, float* Of, int M) {
        k_ln32<<<dim3(M), dim3(256), 0, stream>>>(X, gg, bb, Of);
    };
    auto attn = [&](const float* Q, int qs, const float* Kp, int ks2, const float* Vp, int vs,
                    float* O, int Tq, int Tk) {
        k_attnM<<<dim3(NB * 12), dim3(256), 0, stream>>>(Q, qs, Kp, ks2, Vp, vs, O, D, Tq, Tk);
    };

    auto tblock = [&](float* Xf, int Mtok, int Tseq, int basei, int l) {
        const float* ln1g = IN(basei + 0) + l * D;
        const float* ln1b = IN(basei + 1) + l * D;
        const float* wqkv = IN(basei + 2) + (long long)l * D * 3 * D;
        const float* bqkv = IN(basei + 3) + l * 3 * D;
        const float* wo = IN(basei + 4) + (long long)l * D * D;
        const float* bo = IN(basei + 5) + l * D;
        const float* ln2g = IN(basei + 6) + l * D;
        const float* ln2b = IN(basei + 7) + l * D;
        const float* w1 = IN(basei + 8) + (long long)l * D * FF;
        const float* b1 = IN(basei + 9) + l * FF;
        const float* w2 = IN(basei + 10) + (long long)l * FF * D;
        const float* b2 = IN(basei + 11) + l * D;

        ln(Xf, ln1g, ln1b, h, Mtok);
        gemm(0, h, wqkv, bqkv, nullptr, s1, Mtok, 3 * D, D);              // qkv
        attn(s1, 3 * D, s1 + D, 3 * D, s1 + 2 * D, 3 * D, h, Tseq, Tseq); // self-attn -> h
        gemm(1, h, wo, bo, Xf, Xf, Mtok, D, D);                           // x += ao@wo+bo
        ln(Xf, ln2g, ln2b, h, Mtok);
        gemm(2, h, w1, b1, nullptr, s1, Mtok, FF, D);                     // gelu(h@w1+b1)
        gemm(1, s1, w2, b2, Xf, Xf, Mtok, D, FF);                         // x += ff@w2+b2
    };

    // ---------------- encoder ----------------
    hipMemcpyAsync(x, ctx, (long long)Menc * D * 4, hipMemcpyDeviceToDevice, stream);
    for (int l = 0; l < NL; ++l)
        tblock(x, Menc, S, 5, l);

    // ---------------- decoder ----------------
    k_gather32<<<dim3(Mdec), dim3(256), 0, stream>>>(spe, tpos, flagD, q);
    float* qq = s1;
    float* kk = s1 + (long long)Mdec * D;
    float* vv = kk + (long long)Menc * D;
    for (int l = 0; l < NL; ++l) {
        gemm(0, q, IN(29) + (long long)l * D * D, IN(30) + l * D, nullptr, qq, Mdec, D, D);
        gemm(0, x, IN(31) + (long long)l * D * D, IN(32) + l * D, nullptr, kk, Menc, D, D);
        gemm(0, x, IN(33) + (long long)l * D * D, IN(34) + l * D, nullptr, vv, Menc, D, D);
        attn(qq, D, kk, D, vv, D, h, T, S);                               // cross-attn -> h
        gemm(0, h, IN(35) + (long long)l * D * D, IN(36) + l * D, nullptr, q, Mdec, D, D);
        tblock(q, Mdec, T, 17, l);
    }
    ln(q, norm_g, norm_b, (float*)d_out, Mdec);
}

// Round 12
// 4171.767 us; speedup vs baseline: 28.4691x; 1.0825x over previous
//
#include <hip/hip_runtime.h>

typedef unsigned short u16;
typedef __attribute__((ext_vector_type(8))) __bf16 bf16x8;
typedef __attribute__((ext_vector_type(4))) float f32x4;

#define DEV static __device__ __forceinline__

// arena: flag(256) + bf16 weights(99.1MB) + x + h + s1 + q  (~349.6MB)
#define ARENA_BYTES 349700096ULL
__device__ __align__(256) char g_arena[ARENA_BYTES];

DEV float bf2f(u16 u) { return __uint_as_float(((unsigned)u) << 16); }
DEV u16 f2bf(float f) {
    unsigned u = __float_as_uint(f);
    return (u16)((u + 0x7fffu + ((u >> 16) & 1u)) >> 16);
}
DEV float gelu_tanh(float x) {
    float x3 = x * x * x;
    return 0.5f * x * (1.f + tanhf(0.7978845608028654f * (x + 0.044715f * x3)));
}
// native RNE cast: 8 consecutive fp32 -> 8 bf16 (bit-identical to f2bf for finite vals)
DEV int4 cvt8(const float* p) {
    float4 a = *(const float4*)p, b = *(const float4*)(p + 4);
    union { __bf16 h[8]; int4 v; } t;
    t.h[0] = (__bf16)a.x; t.h[1] = (__bf16)a.y; t.h[2] = (__bf16)a.z; t.h[3] = (__bf16)a.w;
    t.h[4] = (__bf16)b.x; t.h[5] = (__bf16)b.y; t.h[6] = (__bf16)b.z; t.h[7] = (__bf16)b.w;
    return t.v;
}

// ---- target_positions dtype sniff ----
__global__ __launch_bounds__(256) void k_detect_i64(const int* __restrict__ pos, int nhalf,
                                                    int* __restrict__ flagD) {
    int i = blockIdx.x * 256 + threadIdx.x;
    if (i < nhalf && pos[2 * i + 1] != 0) atomicAnd(flagD, 0);
}

// ---- gather rows of spatial_pos_embed ----
__global__ __launch_bounds__(256) void k_gather32(const float* __restrict__ spe,
                                                  const int* __restrict__ pos,
                                                  const int* __restrict__ flagD,
                                                  float* __restrict__ qf) {
    int row = blockIdx.x;
    int p = (*flagD) ? pos[2 * row] : pos[row];
    p = (p < 0) ? 0 : (p > 195 ? 195 : p);
    const float* src = spe + (size_t)p * 768;
    size_t o = (size_t)row * 768;
    for (int i = threadIdx.x; i < 768; i += 256) qf[o + i] = src[i];
}

// ---- LayerNorm over 768 ----
__global__ __launch_bounds__(256) void k_ln32(const float* __restrict__ X,
                                              const float* __restrict__ g,
                                              const float* __restrict__ b,
                                              float* __restrict__ Of) {
    const int row = blockIdx.x, tid = threadIdx.x;
    const float* xr = X + (size_t)row * 768;
    float v0 = xr[tid], v1 = xr[tid + 256], v2 = xr[tid + 512];
    float s = v0 + v1 + v2, s2 = v0 * v0 + v1 * v1 + v2 * v2;
#pragma unroll
    for (int off = 32; off; off >>= 1) {
        s += __shfl_xor(s, off);
        s2 += __shfl_xor(s2, off);
    }
    __shared__ float red[8];
    const int wid = tid >> 6, lane = tid & 63;
    if (lane == 0) { red[wid] = s; red[4 + wid] = s2; }
    __syncthreads();
    s = red[0] + red[1] + red[2] + red[3];
    s2 = red[4] + red[5] + red[6] + red[7];
    const float mu = s * (1.f / 768.f);
    const float var = fmaxf(s2 * (1.f / 768.f) - mu * mu, 0.f);
    const float rs = rsqrtf(var + 1e-5f);
    size_t o = (size_t)row * 768;
#pragma unroll
    for (int i = 0; i < 3; ++i) {
        int c = tid + 256 * i;
        float vv = (i == 0 ? v0 : (i == 1 ? v1 : v2));
        Of[o + c] = (vv - mu) * rs * g[c] + b[c];
    }
}

// ---- weight transpose + fp32->bf16 convert: W[K,N] -> WT[N,K]  [proven r7-r9] ----
__global__ __launch_bounds__(256) void k_wtrans(const float* __restrict__ W,
                                                u16* __restrict__ WT, int K, int N) {
    int idx = blockIdx.x * 256 + threadIdx.x;
    int tot = N * (K >> 3);
    if (idx >= tot) return;
    int n = idx % N;
    int kc = idx / N;
    union { u16 u[8]; int4 v; } tmp;
#pragma unroll
    for (int j = 0; j < 8; ++j) tmp.u[j] = f2bf(W[(size_t)(kc * 8 + j) * N + n]);
    *(int4*)&WT[(size_t)n * K + kc * 8] = tmp.v;
}

// ---- MFMA GEMM: C[M,N] = A32[M,K] @ BT[N,K]^T + bias (+gelu/+res)  [r7-proven core] ----
// 128x128 tile, BK=32, 4 waves (2x2), fragments per HW-verified m89/m91 layout.
template <bool GELU_, bool RES_>
__global__ __launch_bounds__(256) void k_gemmM(const float* __restrict__ A,
                                               const u16* __restrict__ BT,
                                               const float* __restrict__ bias,
                                               const float* __restrict__ R,
                                               float* __restrict__ C,
                                               int M, int N, int K) {
    __shared__ __align__(16) u16 Asm[128 * 32];
    __shared__ __align__(16) u16 Bsm[128 * 32];
    const int tid = threadIdx.x;
    const int lane = tid & 63;
    const int wid = tid >> 6;
    const int wm = wid >> 1, wn = wid & 1;
    const size_t Abase = (size_t)blockIdx.x * 128 * K;   // float elements
    const size_t Bbase = (size_t)blockIdx.y * 128 * K;   // u16 elements

    f32x4 acc[4][4] = {};
    const int r0 = tid >> 2;
    const int ko0 = (tid & 3) * 8;

    for (int k0 = 0; k0 < K; k0 += 32) {
        const float* Ag0 = A + Abase + (size_t)r0 * K + k0 + ko0;
        *(int4*)&Asm[tid * 8] = cvt8(Ag0);
        *(int4*)&Asm[(256 + tid) * 8] = cvt8(Ag0 + (size_t)64 * K);
        const u16* Bg = BT + Bbase + (size_t)r0 * K + k0 + ko0;
        *(int4*)&Bsm[tid * 8] = *(const int4*)Bg;
        *(int4*)&Bsm[(256 + tid) * 8] = *(const int4*)(Bg + (size_t)64 * K);
        __syncthreads();

        const int fr = lane & 15, g = lane >> 4;
        bf16x8 af[4], bfr[4];
#pragma unroll
        for (int i = 0; i < 4; ++i) {
            af[i] = *(const bf16x8*)&Asm[(wm * 64 + i * 16 + fr) * 32 + g * 8];
            bfr[i] = *(const bf16x8*)&Bsm[(wn * 64 + i * 16 + fr) * 32 + g * 8];
        }
#pragma unroll
        for (int i = 0; i < 4; ++i)
#pragma unroll
            for (int j = 0; j < 4; ++j)
                acc[i][j] = __builtin_amdgcn_mfma_f32_16x16x32_bf16(af[i], bfr[j], acc[i][j], 0, 0, 0);
        __syncthreads();
    }

    // C/D layout: col=lane&15, row=(lane>>4)*4+reg  [HW-verified m89/m91]
    const int fr = lane & 15, g4 = (lane >> 4) * 4;
#pragma unroll
    for (int j = 0; j < 4; ++j) {
        const int col = blockIdx.y * 128 + wn * 64 + j * 16 + fr;
        const float bc = bias[col];
#pragma unroll
        for (int i = 0; i < 4; ++i) {
#pragma unroll
            for (int r = 0; r < 4; ++r) {
                const int row = blockIdx.x * 128 + wm * 64 + i * 16 + g4 + r;
                float v = acc[i][j][r] + bc;
                if (GELU_) v = gelu_tanh(v);
                if (RES_)  v += R[(size_t)row * N + col];
                C[(size_t)row * N + col] = v;
            }
        }
    }
}

// ---- load 8 consecutive fp32 -> bf16x8 ----
DEV bf16x8 ldq8(const float* p) {
    float4 a = *(const float4*)p, b = *(const float4*)(p + 4);
    union { u16 u[8]; bf16x8 v; } t;
    t.u[0] = f2bf(a.x); t.u[1] = f2bf(a.y); t.u[2] = f2bf(a.z); t.u[3] = f2bf(a.w);
    t.u[4] = f2bf(b.x); t.u[5] = f2bf(b.y); t.u[6] = f2bf(b.z); t.u[7] = f2bf(b.w);
    return t.v;
}

// ---- MFMA flash attention (unchanged from passing r11) ----
__global__ __launch_bounds__(256) void k_attnM(const float* __restrict__ Qp, int qs,
                                               const float* __restrict__ Kp, int ks,
                                               const float* __restrict__ Vp, int vs,
                                               float* __restrict__ Op, int os,
                                               int Tq, int Tk) {
    __shared__ u16 kl[208][72];
    __shared__ u16 vt[64][272];
    __shared__ u16 pl[4][16][72];
    const int bh = blockIdx.x, b = bh / 12, h = bh % 12;
    const int tid = threadIdx.x, lane = tid & 63, wid = tid >> 6;
    const int fr = lane & 15, g = lane >> 4, g4 = g * 4;

    const int Tkp = (Tk + 15) & ~15;
    const int NC = (Tkp + 63) >> 6;
    const int TC = NC << 6;

    for (int r = wid; r < Tkp; r += 4) {
        float kv = (r < Tk) ? Kp[((size_t)b * Tk + r) * ks + h * 64 + lane] : 0.f;
        kl[r][lane] = f2bf(kv);
    }
    for (int t = wid; t < TC; t += 4) {
        float vv = (t < Tk) ? Vp[((size_t)b * Tk + t) * vs + h * 64 + lane] : 0.f;
        vt[lane][t] = f2bf(vv);
    }
    __syncthreads();

    const int NT = (Tq + 63) >> 6;
    for (int it = 0; it < NT; ++it) {
        const int qb = (it << 6) + (wid << 4);
        if (qb >= Tq) continue;

        int qr = qb + fr;
        if (qr >= Tq) qr = 0;
        const float* Qrow = Qp + ((size_t)b * Tq + qr) * qs + h * 64;
        bf16x8 afq0 = ldq8(Qrow + g * 8);
        bf16x8 afq1 = ldq8(Qrow + 32 + g * 8);

        f32x4 acc_o[4] = {};
        float m_r[4] = {-1e30f, -1e30f, -1e30f, -1e30f};
        float lp[4] = {0.f, 0.f, 0.f, 0.f};

        for (int c = 0; c < NC; ++c) {
            const int tk0 = c << 6;
            int NF = (Tkp - tk0) >> 4;
            if (NF > 4) NF = 4;

            f32x4 acc_s[4] = {};
#pragma unroll
            for (int nf = 0; nf < 4; ++nf) {
                if (nf < NF) {
                    const u16* kr = &kl[tk0 + nf * 16 + fr][0];
                    acc_s[nf] = __builtin_amdgcn_mfma_f32_16x16x32_bf16(
                        afq0, *(const bf16x8*)&kr[g * 8], acc_s[nf], 0, 0, 0);
                    acc_s[nf] = __builtin_amdgcn_mfma_f32_16x16x32_bf16(
                        afq1, *(const bf16x8*)&kr[32 + g * 8], acc_s[nf], 0, 0, 0);
                }
            }
            float pm[4] = {-1e30f, -1e30f, -1e30f, -1e30f};
#pragma unroll
            for (int nf = 0; nf < 4; ++nf) {
                if (nf < NF) {
                    const bool cv = (tk0 + nf * 16 + fr) < Tk;
#pragma unroll
                    for (int r = 0; r < 4; ++r) {
                        float sv = acc_s[nf][r] * 0.125f;
                        acc_s[nf][r] = sv;
                        if (cv) pm[r] = fmaxf(pm[r], sv);
                    }
                }
            }
#pragma unroll
            for (int off = 1; off < 16; off <<= 1)
#pragma unroll
                for (int r = 0; r < 4; ++r) pm[r] = fmaxf(pm[r], __shfl_xor(pm[r], off));
            float al[4];
#pragma unroll
            for (int r = 0; r < 4; ++r) {
                float mn = fmaxf(m_r[r], pm[r]);
                al[r] = __expf(m_r[r] - mn);
                m_r[r] = mn;
                lp[r] *= al[r];
            }
#pragma unroll
            for (int nfd = 0; nfd < 4; ++nfd)
#pragma unroll
                for (int r = 0; r < 4; ++r) acc_o[nfd][r] *= al[r];
#pragma unroll
            for (int nf = 0; nf < 4; ++nf) {
                const bool cv = (nf < NF) && ((tk0 + nf * 16 + fr) < Tk);
#pragma unroll
                for (int r = 0; r < 4; ++r) {
                    float w = cv ? __expf(acc_s[nf][r] - m_r[r]) : 0.f;
                    lp[r] += w;
                    pl[wid][g4 + r][nf * 16 + fr] = f2bf(w);
                }
            }
#pragma unroll
            for (int ksp = 0; ksp < 2; ++ksp) {
                bf16x8 ap = *(const bf16x8*)&pl[wid][fr][ksp * 32 + g * 8];
#pragma unroll
                for (int nfd = 0; nfd < 4; ++nfd)
                    acc_o[nfd] = __builtin_amdgcn_mfma_f32_16x16x32_bf16(
                        ap, *(const bf16x8*)&vt[nfd * 16 + fr][tk0 + ksp * 32 + g * 8],
                        acc_o[nfd], 0, 0, 0);
            }
        }
#pragma unroll
        for (int off = 1; off < 16; off <<= 1)
#pragma unroll
            for (int r = 0; r < 4; ++r) lp[r] += __shfl_xor(lp[r], off);
#pragma unroll
        for (int r = 0; r < 4; ++r) {
            int qrow = qb + g4 + r;
            if (qrow < Tq) {
                float inv = 1.f / lp[r];
#pragma unroll
                for (int nfd = 0; nfd < 4; ++nfd)
                    Op[((size_t)b * Tq + qrow) * os + h * 64 + nfd * 16 + fr] =
                        acc_o[nfd][r] * inv;
            }
        }
    }
}

// =======================================================================================
extern "C" void kernel_launch(void* const* d_in, const int* in_sizes, int n_in,
                              void* d_out, int out_size, void* d_ws, size_t ws_size,
                              hipStream_t stream) {
    const int D = 768, FF = 3072, NB = 64, S = 196, T = 98, NL = 3;
    const int Menc = NB * S;   // 12544
    const int Mdec = NB * T;   // 6272

    auto IN = [&](int i) { return (const float*)d_in[i]; };
    const float* ctx = IN(0);
    const int* tpos = (const int*)d_in[1];
    const float* spe = IN(2);
    const float* norm_g = IN(3);
    const float* norm_b = IN(4);

    char* base;
    if (ws_size >= ARENA_BYTES) {
        base = (char*)d_ws;
    } else {
        void* sym = nullptr;
        if (hipGetSymbolAddress(&sym, HIP_SYMBOL(g_arena)) == hipSuccess && sym)
            base = (char*)sym;
        else
            base = (char*)d_ws;
    }
    char* pp = base;
    auto alloc = [&](long long bytes) -> void* {
        void* r = (void*)pp;
        pp += (bytes + 255) & ~255LL;
        return r;
    };
    int* flag = (int*)alloc(256);
    int* flagD = flag + 1;

    // ---- one-time weight pre-conversion: W[K,N] fp32 -> WT[N,K] bf16 ----
    auto cvw = [&](const float* W, int K, int N) -> u16* {
        u16* dst = (u16*)alloc((long long)K * N * 2);
        int tot = N * (K / 8);
        k_wtrans<<<dim3((tot + 255) / 256), dim3(256), 0, stream>>>(W, dst, K, N);
        return dst;
    };
    u16 *encW[3][4], *decW[3][4], *caW[3][4];
    for (int l = 0; l < NL; ++l) {
        encW[l][0] = cvw(IN(7) + (long long)l * D * 3 * D, D, 3 * D);   // wqkv
        encW[l][1] = cvw(IN(9) + (long long)l * D * D, D, D);           // wo
        encW[l][2] = cvw(IN(13) + (long long)l * D * FF, D, FF);        // w1
        encW[l][3] = cvw(IN(15) + (long long)l * FF * D, FF, D);        // w2
    }
    for (int l = 0; l < NL; ++l) {
        decW[l][0] = cvw(IN(19) + (long long)l * D * 3 * D, D, 3 * D);
        decW[l][1] = cvw(IN(21) + (long long)l * D * D, D, D);
        decW[l][2] = cvw(IN(25) + (long long)l * D * FF, D, FF);
        decW[l][3] = cvw(IN(27) + (long long)l * FF * D, FF, D);
    }
    for (int l = 0; l < NL; ++l) {
        caW[l][0] = cvw(IN(29) + (long long)l * D * D, D, D);           // wq
        caW[l][1] = cvw(IN(31) + (long long)l * D * D, D, D);           // wk
        caW[l][2] = cvw(IN(33) + (long long)l * D * D, D, D);           // wv
        caW[l][3] = cvw(IN(35) + (long long)l * D * D, D, D);           // wo
    }

    float* x = (float*)alloc((long long)Menc * D * 4);
    float* h = (float*)alloc((long long)Menc * D * 4);
    float* s1 = (float*)alloc((long long)Menc * FF * 4);
    float* q = (float*)alloc((long long)Mdec * D * 4);

    hipMemsetAsync(flagD, 0x01, 4, stream);
    k_detect_i64<<<dim3((Mdec / 2 + 255) / 256), dim3(256), 0, stream>>>(tpos, Mdec / 2, flagD);

    // mode 0: plain, 1: +residual, 2: gelu
    auto gemm = [&](int mode, const float* A, const u16* WT, const float* bias,
                    const float* R, float* C, int M, int N, int K) {
        dim3 g(M / 128, N / 128), blk(256);
        if (mode == 0)      k_gemmM<false, false><<<g, blk, 0, stream>>>(A, WT, bias, nullptr, C, M, N, K);
        else if (mode == 1) k_gemmM<false, true><<<g, blk, 0, stream>>>(A, WT, bias, R, C, M, N, K);
        else                k_gemmM<true, false><<<g, blk, 0, stream>>>(A, WT, bias, nullptr, C, M, N, K);
    };
    auto ln = [&](const float* X, const float* gg, const float* bb, float* Of, int M) {
        k_ln32<<<dim3(M), dim3(256), 0, stream>>>(X, gg, bb, Of);
    };
    auto attn = [&](const float* Q, int qs, const float* Kp, int ks2, const float* Vp, int vs,
                    float* O, int Tq, int Tk) {
        k_attnM<<<dim3(NB * 12), dim3(256), 0, stream>>>(Q, qs, Kp, ks2, Vp, vs, O, D, Tq, Tk);
    };

    auto tblock = [&](float* Xf, int Mtok, int Tseq, int basei, u16* const* Wl) {
        const float* ln1g = IN(basei + 0);
        const float* ln1b = IN(basei + 1);
        const float* bqkv = IN(basei + 3);
        const float* bo = IN(basei + 5);
        const float* ln2g = IN(basei + 6);
        const float* ln2b = IN(basei + 7);
        const float* b1 = IN(basei + 9);
        const float* b2 = IN(basei + 11);

        ln(Xf, ln1g, ln1b, h, Mtok);
        gemm(0, h, Wl[0], bqkv, nullptr, s1, Mtok, 3 * D, D);             // qkv
        attn(s1, 3 * D, s1 + D, 3 * D, s1 + 2 * D, 3 * D, h, Tseq, Tseq); // self-attn -> h
        gemm(1, h, Wl[1], bo, Xf, Xf, Mtok, D, D);                        // x += ao@wo+bo
        ln(Xf, ln2g, ln2b, h, Mtok);
        gemm(2, h, Wl[2], b1, nullptr, s1, Mtok, FF, D);                  // gelu(h@w1+b1)
        gemm(1, s1, Wl[3], b2, Xf, Xf, Mtok, D, FF);                      // x += ff@w2+b2
    };

    // ---------------- encoder ----------------
    hipMemcpyAsync(x, ctx, (long long)Menc * D * 4, hipMemcpyDeviceToDevice, stream);
    for (int l = 0; l < NL; ++l) {
        // per-layer bias/ln offsets: pass shifted pointers via a small shim
        const float* saved[1];
        (void)saved;
        // build shifted views
        // (biases/ln are [L, D]-shaped; shift by l)
        // simplest: temporary lambda capturing l
        auto tb = [&](float* Xf, int Mtok, int Tseq, int basei, u16* const* Wl) {
            const float* ln1g = IN(basei + 0) + l * D;
            const float* ln1b = IN(basei + 1) + l * D;
            const float* bqkv = IN(basei + 3) + l * 3 * D;
            const float* bo = IN(basei + 5) + l * D;
            const float* ln2g = IN(basei + 6) + l * D;
            const float* ln2b = IN(basei + 7) + l * D;
            const float* b1 = IN(basei + 9) + l * FF;
            const float* b2 = IN(basei + 11) + l * D;
            ln(Xf, ln1g, ln1b, h, Mtok);
            gemm(0, h, Wl[0], bqkv, nullptr, s1, Mtok, 3 * D, D);
            attn(s1, 3 * D, s1 + D, 3 * D, s1 + 2 * D, 3 * D, h, Tseq, Tseq);
            gemm(1, h, Wl[1], bo, Xf, Xf, Mtok, D, D);
            ln(Xf, ln2g, ln2b, h, Mtok);
            gemm(2, h, Wl[2], b1, nullptr, s1, Mtok, FF, D);
            gemm(1, s1, Wl[3], b2, Xf, Xf, Mtok, D, FF);
        };
        tb(x, Menc, S, 5, encW[l]);
    }
    (void)tblock;

    // ---------------- decoder ----------------
    k_gather32<<<dim3(Mdec), dim3(256), 0, stream>>>(spe, tpos, flagD, q);
    float* qq = s1;
    float* kk = s1 + (long long)Mdec * D;
    float* vv = kk + (long long)Menc * D;
    for (int l = 0; l < NL; ++l) {
        gemm(0, q, caW[l][0], IN(30) + l * D, nullptr, qq, Mdec, D, D);
        gemm(0, x, caW[l][1], IN(32) + l * D, nullptr, kk, Menc, D, D);
        gemm(0, x, caW[l][2], IN(34) + l * D, nullptr, vv, Menc, D, D);
        attn(qq, D, kk, D, vv, D, h, T, S);
        gemm(0, h, caW[l][3], IN(36) + l * D, nullptr, q, Mdec, D, D);
        auto tb = [&](float* Xf, int Mtok, int Tseq, int basei, u16* const* Wl) {
            const float* ln1g = IN(basei + 0) + l * D;
            const float* ln1b = IN(basei + 1) + l * D;
            const float* bqkv = IN(basei + 3) + l * 3 * D;
            const float* bo = IN(basei + 5) + l * D;
            const float* ln2g = IN(basei + 6) + l * D;
            const float* ln2b = IN(basei + 7) + l * D;
            const float* b1 = IN(basei + 9) + l * FF;
            const float* b2 = IN(basei + 11) + l * D;
            ln(Xf, ln1g, ln1b, h, Mtok);
            gemm(0, h, Wl[0], bqkv, nullptr, s1, Mtok, 3 * D, D);
            attn(s1, 3 * D, s1 + D, 3 * D, s1 + 2 * D, 3 * D, h, Tseq, Tseq);
            gemm(1, h, Wl[1], bo, Xf, Xf, Mtok, D, D);
            ln(Xf, ln2g, ln2b, h, Mtok);
            gemm(2, h, Wl[2], b1, nullptr, s1, Mtok, FF, D);
            gemm(1, s1, Wl[3], b2, Xf, Xf, Mtok, D, FF);
        };
        tb(q, Mdec, T, 17, decW[l]);
    }
    ln(q, norm_g, norm_b, (float*)d_out, Mdec);
}

// Round 13
// 3726.256 us; speedup vs baseline: 31.8729x; 1.1196x over previous
//
#include <hip/hip_runtime.h>

typedef unsigned short u16;
typedef __attribute__((ext_vector_type(8))) __bf16 bf16x8;
typedef __attribute__((ext_vector_type(4))) float f32x4;

#define DEV static __device__ __forceinline__

#define ARENA_BYTES 349700096ULL
__device__ __align__(256) char g_arena[ARENA_BYTES];

DEV float bf2f(u16 u) { return __uint_as_float(((unsigned)u) << 16); }
DEV u16 f2bf(float f) {
    unsigned u = __float_as_uint(f);
    return (u16)((u + 0x7fffu + ((u >> 16) & 1u)) >> 16);
}
DEV float gelu_tanh(float x) {
    float x3 = x * x * x;
    return 0.5f * x * (1.f + tanhf(0.7978845608028654f * (x + 0.044715f * x3)));
}

// ---- async global->LDS, 16B per lane (m97 pattern; lane i -> ldsbase + i*16) ----
DEV void gload16(const u16* gp, u16* lp) {
    __builtin_amdgcn_global_load_lds((const __attribute__((address_space(1))) void*)gp,
                                     (__attribute__((address_space(3))) void*)lp, 16, 0, 0);
}

// ---- target_positions dtype sniff ----
__global__ __launch_bounds__(256) void k_detect_i64(const int* __restrict__ pos, int nhalf,
                                                    int* __restrict__ flagD) {
    int i = blockIdx.x * 256 + threadIdx.x;
    if (i < nhalf && pos[2 * i + 1] != 0) atomicAnd(flagD, 0);
}

// ---- gather rows of spatial_pos_embed -> bf16 ----
__global__ __launch_bounds__(256) void k_gatherB(const float* __restrict__ spe,
                                                 const int* __restrict__ pos,
                                                 const int* __restrict__ flagD,
                                                 u16* __restrict__ qb) {
    int row = blockIdx.x;
    int p = (*flagD) ? pos[2 * row] : pos[row];
    p = (p < 0) ? 0 : (p > 195 ? 195 : p);
    const float* src = spe + (size_t)p * 768;
    size_t o = (size_t)row * 768;
    for (int i = threadIdx.x; i < 768; i += 256) qb[o + i] = f2bf(src[i]);
}

// ---- LayerNorm over 768: fp32 in, bf16 out (OUTF32=0) or fp32 out (final) ----
template <int OUTF32>
__global__ __launch_bounds__(256) void k_ln(const float* __restrict__ X,
                                            const float* __restrict__ g,
                                            const float* __restrict__ b,
                                            u16* __restrict__ Ob, float* __restrict__ Of) {
    const int row = blockIdx.x, tid = threadIdx.x;
    const float* xr = X + (size_t)row * 768;
    float v0 = xr[tid], v1 = xr[tid + 256], v2 = xr[tid + 512];
    float s = v0 + v1 + v2, s2 = v0 * v0 + v1 * v1 + v2 * v2;
#pragma unroll
    for (int off = 32; off; off >>= 1) {
        s += __shfl_xor(s, off);
        s2 += __shfl_xor(s2, off);
    }
    __shared__ float red[8];
    const int wid = tid >> 6, lane = tid & 63;
    if (lane == 0) { red[wid] = s; red[4 + wid] = s2; }
    __syncthreads();
    s = red[0] + red[1] + red[2] + red[3];
    s2 = red[4] + red[5] + red[6] + red[7];
    const float mu = s * (1.f / 768.f);
    const float var = fmaxf(s2 * (1.f / 768.f) - mu * mu, 0.f);
    const float rs = rsqrtf(var + 1e-5f);
    size_t o = (size_t)row * 768;
#pragma unroll
    for (int i = 0; i < 3; ++i) {
        int c = tid + 256 * i;
        float vv = (i == 0 ? v0 : (i == 1 ? v1 : v2));
        float y = (vv - mu) * rs * g[c] + b[c];
        if (OUTF32) Of[o + c] = y;
        else        Ob[o + c] = f2bf(y);
    }
}

// ---- weight transpose + fp32->bf16 convert: W[K,N] -> WT[N,K] ----
__global__ __launch_bounds__(256) void k_wtrans(const float* __restrict__ W,
                                                u16* __restrict__ WT, int K, int N) {
    int idx = blockIdx.x * 256 + threadIdx.x;
    int tot = N * (K >> 3);
    if (idx >= tot) return;
    int n = idx % N;
    int kc = idx / N;
    union { u16 u[8]; int4 v; } tmp;
#pragma unroll
    for (int j = 0; j < 8; ++j) tmp.u[j] = f2bf(W[(size_t)(kc * 8 + j) * N + n]);
    *(int4*)&WT[(size_t)n * K + kc * 8] = tmp.v;
}

// ---- bf16 MFMA GEMM, global_load_lds staging:
//      C = Ab[M,K] @ BT[N,K]^T + bias (+gelu/+res); fp32 and/or bf16 outputs.
//      128x128 tile, BK=32, 4 waves (2x2); fragments per HW-verified m89/m91 layout. ----
template <bool GELU_, bool RES_, bool OF32, bool OBF>
__global__ __launch_bounds__(256) void k_gemmB(const u16* __restrict__ A,
                                               const u16* __restrict__ BT,
                                               const float* __restrict__ bias,
                                               const float* __restrict__ R,
                                               float* __restrict__ Cf, u16* __restrict__ Cb,
                                               int M, int N, int K) {
    __shared__ __align__(16) u16 Asm[128 * 32];
    __shared__ __align__(16) u16 Bsm[128 * 32];
    const int tid = threadIdx.x;
    const int lane = tid & 63;
    const int wid = tid >> 6;
    const int wm = wid >> 1, wn = wid & 1;
    const size_t Abase = (size_t)blockIdx.x * 128 * K;
    const size_t Bbase = (size_t)blockIdx.y * 128 * K;

    f32x4 acc[4][4] = {};
    const int r_in = lane >> 2;          // row within 16-row group
    const int kof = (lane & 3) * 8;      // k-offset within 32

    for (int k0 = 0; k0 < K; k0 += 32) {
        // per wave: rows wid*32 .. wid*32+31 of A and B tiles, 2 instrs each
#pragma unroll
        for (int n = 0; n < 2; ++n) {
            const int rg = wid * 32 + n * 16;
            gload16(A + Abase + (size_t)(rg + r_in) * K + k0 + kof, &Asm[rg * 32]);
            gload16(BT + Bbase + (size_t)(rg + r_in) * K + k0 + kof, &Bsm[rg * 32]);
        }
        __syncthreads();   // drains vmcnt -> LDS valid

        const int fr = lane & 15, g = lane >> 4;
        bf16x8 af[4], bfr[4];
#pragma unroll
        for (int i = 0; i < 4; ++i) {
            af[i] = *(const bf16x8*)&Asm[(wm * 64 + i * 16 + fr) * 32 + g * 8];
            bfr[i] = *(const bf16x8*)&Bsm[(wn * 64 + i * 16 + fr) * 32 + g * 8];
        }
#pragma unroll
        for (int i = 0; i < 4; ++i)
#pragma unroll
            for (int j = 0; j < 4; ++j)
                acc[i][j] = __builtin_amdgcn_mfma_f32_16x16x32_bf16(af[i], bfr[j], acc[i][j], 0, 0, 0);
        __syncthreads();
    }

    // C/D layout: col=lane&15, row=(lane>>4)*4+reg  [HW-verified m89/m91]
    const int fr = lane & 15, g4 = (lane >> 4) * 4;
#pragma unroll
    for (int j = 0; j < 4; ++j) {
        const int col = blockIdx.y * 128 + wn * 64 + j * 16 + fr;
        const float bc = bias[col];
#pragma unroll
        for (int i = 0; i < 4; ++i) {
#pragma unroll
            for (int r = 0; r < 4; ++r) {
                const int row = blockIdx.x * 128 + wm * 64 + i * 16 + g4 + r;
                float v = acc[i][j][r] + bc;
                if (GELU_) v = gelu_tanh(v);
                if (RES_)  v += R[(size_t)row * N + col];
                if (OF32)  Cf[(size_t)row * N + col] = v;
                if (OBF)   Cb[(size_t)row * N + col] = f2bf(v);
            }
        }
    }
}

// ---- MFMA flash attention, bf16 in / bf16 out (structure proven r11) ----
__global__ __launch_bounds__(256) void k_attnM(const u16* __restrict__ Qp, int qs,
                                               const u16* __restrict__ Kp, int ks,
                                               const u16* __restrict__ Vp, int vs,
                                               u16* __restrict__ Op, int os,
                                               int Tq, int Tk) {
    __shared__ u16 kl[208][72];
    __shared__ u16 vt[64][272];
    __shared__ u16 pl[4][16][72];
    const int bh = blockIdx.x, b = bh / 12, h = bh % 12;
    const int tid = threadIdx.x, lane = tid & 63, wid = tid >> 6;
    const int fr = lane & 15, g = lane >> 4, g4 = g * 4;

    const int Tkp = (Tk + 15) & ~15;
    const int NC = (Tkp + 63) >> 6;
    const int TC = NC << 6;

    for (int r = wid; r < Tkp; r += 4) {
        kl[r][lane] = (r < Tk) ? Kp[((size_t)b * Tk + r) * ks + h * 64 + lane] : (u16)0;
    }
    for (int t = wid; t < TC; t += 4) {
        vt[lane][t] = (t < Tk) ? Vp[((size_t)b * Tk + t) * vs + h * 64 + lane] : (u16)0;
    }
    __syncthreads();

    const int NT = (Tq + 63) >> 6;
    for (int it = 0; it < NT; ++it) {
        const int qb = (it << 6) + (wid << 4);
        if (qb >= Tq) continue;

        int qr = qb + fr;
        if (qr >= Tq) qr = 0;
        const u16* Qrow = Qp + ((size_t)b * Tq + qr) * qs + h * 64;
        bf16x8 afq0 = *(const bf16x8*)&Qrow[g * 8];
        bf16x8 afq1 = *(const bf16x8*)&Qrow[32 + g * 8];

        f32x4 acc_o[4] = {};
        float m_r[4] = {-1e30f, -1e30f, -1e30f, -1e30f};
        float lp[4] = {0.f, 0.f, 0.f, 0.f};

        for (int c = 0; c < NC; ++c) {
            const int tk0 = c << 6;
            int NF = (Tkp - tk0) >> 4;
            if (NF > 4) NF = 4;

            f32x4 acc_s[4] = {};
#pragma unroll
            for (int nf = 0; nf < 4; ++nf) {
                if (nf < NF) {
                    const u16* kr = &kl[tk0 + nf * 16 + fr][0];
                    acc_s[nf] = __builtin_amdgcn_mfma_f32_16x16x32_bf16(
                        afq0, *(const bf16x8*)&kr[g * 8], acc_s[nf], 0, 0, 0);
                    acc_s[nf] = __builtin_amdgcn_mfma_f32_16x16x32_bf16(
                        afq1, *(const bf16x8*)&kr[32 + g * 8], acc_s[nf], 0, 0, 0);
                }
            }
            float pm[4] = {-1e30f, -1e30f, -1e30f, -1e30f};
#pragma unroll
            for (int nf = 0; nf < 4; ++nf) {
                if (nf < NF) {
                    const bool cv = (tk0 + nf * 16 + fr) < Tk;
#pragma unroll
                    for (int r = 0; r < 4; ++r) {
                        float sv = acc_s[nf][r] * 0.125f;
                        acc_s[nf][r] = sv;
                        if (cv) pm[r] = fmaxf(pm[r], sv);
                    }
                }
            }
#pragma unroll
            for (int off = 1; off < 16; off <<= 1)
#pragma unroll
                for (int r = 0; r < 4; ++r) pm[r] = fmaxf(pm[r], __shfl_xor(pm[r], off));
            float al[4];
#pragma unroll
            for (int r = 0; r < 4; ++r) {
                float mn = fmaxf(m_r[r], pm[r]);
                al[r] = __expf(m_r[r] - mn);
                m_r[r] = mn;
                lp[r] *= al[r];
            }
#pragma unroll
            for (int nfd = 0; nfd < 4; ++nfd)
#pragma unroll
                for (int r = 0; r < 4; ++r) acc_o[nfd][r] *= al[r];
#pragma unroll
            for (int nf = 0; nf < 4; ++nf) {
                const bool cv = (nf < NF) && ((tk0 + nf * 16 + fr) < Tk);
#pragma unroll
                for (int r = 0; r < 4; ++r) {
                    float w = cv ? __expf(acc_s[nf][r] - m_r[r]) : 0.f;
                    lp[r] += w;
                    pl[wid][g4 + r][nf * 16 + fr] = f2bf(w);
                }
            }
#pragma unroll
            for (int ksp = 0; ksp < 2; ++ksp) {
                bf16x8 ap = *(const bf16x8*)&pl[wid][fr][ksp * 32 + g * 8];
#pragma unroll
                for (int nfd = 0; nfd < 4; ++nfd)
                    acc_o[nfd] = __builtin_amdgcn_mfma_f32_16x16x32_bf16(
                        ap, *(const bf16x8*)&vt[nfd * 16 + fr][tk0 + ksp * 32 + g * 8],
                        acc_o[nfd], 0, 0, 0);
            }
        }
#pragma unroll
        for (int off = 1; off < 16; off <<= 1)
#pragma unroll
            for (int r = 0; r < 4; ++r) lp[r] += __shfl_xor(lp[r], off);
#pragma unroll
        for (int r = 0; r < 4; ++r) {
            int qrow = qb + g4 + r;
            if (qrow < Tq) {
                float inv = 1.f / lp[r];
#pragma unroll
                for (int nfd = 0; nfd < 4; ++nfd)
                    Op[((size_t)b * Tq + qrow) * os + h * 64 + nfd * 16 + fr] =
                        f2bf(acc_o[nfd][r] * inv);
            }
        }
    }
}

// =======================================================================================
extern "C" void kernel_launch(void* const* d_in, const int* in_sizes, int n_in,
                              void* d_out, int out_size, void* d_ws, size_t ws_size,
                              hipStream_t stream) {
    const int D = 768, FF = 3072, NB = 64, S = 196, T = 98, NL = 3;
    const int Menc = NB * S;   // 12544
    const int Mdec = NB * T;   // 6272

    auto IN = [&](int i) { return (const float*)d_in[i]; };
    const int* tpos = (const int*)d_in[1];
    const float* spe = IN(2);
    const float* norm_g = IN(3);
    const float* norm_b = IN(4);

    char* base;
    if (ws_size >= ARENA_BYTES) {
        base = (char*)d_ws;
    } else {
        void* sym = nullptr;
        if (hipGetSymbolAddress(&sym, HIP_SYMBOL(g_arena)) == hipSuccess && sym)
            base = (char*)sym;
        else
            base = (char*)d_ws;
    }
    char* pp = base;
    auto alloc = [&](long long bytes) -> void* {
        void* r = (void*)pp;
        pp += (bytes + 255) & ~255LL;
        return r;
    };
    int* flag = (int*)alloc(256);
    int* flagD = flag + 1;

    // ---- one-time weight pre-conversion: W[K,N] fp32 -> WT[N,K] bf16 ----
    auto cvw = [&](const float* W, int K, int N) -> u16* {
        u16* dst = (u16*)alloc((long long)K * N * 2);
        int tot = N * (K / 8);
        k_wtrans<<<dim3((tot + 255) / 256), dim3(256), 0, stream>>>(W, dst, K, N);
        return dst;
    };
    u16 *encW[3][4], *decW[3][4], *caW[3][4];
    for (int l = 0; l < NL; ++l) {
        encW[l][0] = cvw(IN(7) + (long long)l * D * 3 * D, D, 3 * D);
        encW[l][1] = cvw(IN(9) + (long long)l * D * D, D, D);
        encW[l][2] = cvw(IN(13) + (long long)l * D * FF, D, FF);
        encW[l][3] = cvw(IN(15) + (long long)l * FF * D, FF, D);
    }
    for (int l = 0; l < NL; ++l) {
        decW[l][0] = cvw(IN(19) + (long long)l * D * 3 * D, D, 3 * D);
        decW[l][1] = cvw(IN(21) + (long long)l * D * D, D, D);
        decW[l][2] = cvw(IN(25) + (long long)l * D * FF, D, FF);
        decW[l][3] = cvw(IN(27) + (long long)l * FF * D, FF, D);
    }
    for (int l = 0; l < NL; ++l) {
        caW[l][0] = cvw(IN(29) + (long long)l * D * D, D, D);
        caW[l][1] = cvw(IN(31) + (long long)l * D * D, D, D);
        caW[l][2] = cvw(IN(33) + (long long)l * D * D, D, D);
        caW[l][3] = cvw(IN(35) + (long long)l * D * D, D, D);
    }

    float* x = (float*)alloc((long long)Menc * D * 4);   // fp32 residual (enc)
    float* q = (float*)alloc((long long)Mdec * D * 4);   // fp32 residual (dec)
    u16* xb = (u16*)alloc((long long)Menc * D * 2);      // bf16 mirror of x
    u16* qb = (u16*)alloc((long long)Mdec * D * 2);      // bf16 mirror of q
    u16* hb = (u16*)alloc((long long)Menc * D * 2);      // bf16 LN/attn out
    u16* s1b = (u16*)alloc((long long)Menc * FF * 2);    // bf16 qkv / ff1 / dec qq,kk,vv

    hipMemsetAsync(flagD, 0x01, 4, stream);
    k_detect_i64<<<dim3((Mdec / 2 + 255) / 256), dim3(256), 0, stream>>>(tpos, Mdec / 2, flagD);

    // modes: 0 plain->bf16 | 1 res->fp32+bf16 | 2 gelu->bf16 | 3 plain->fp32+bf16
    auto gemm = [&](int mode, const u16* A, const u16* WT, const float* bias,
                    const float* R, float* Cf, u16* Cb, int M, int N, int K) {
        dim3 g(M / 128, N / 128), blk(256);
        switch (mode) {
            case 0: k_gemmB<false, false, false, true><<<g, blk, 0, stream>>>(A, WT, bias, nullptr, nullptr, Cb, M, N, K); break;
            case 1: k_gemmB<false, true, true, true><<<g, blk, 0, stream>>>(A, WT, bias, R, Cf, Cb, M, N, K); break;
            case 2: k_gemmB<true, false, false, true><<<g, blk, 0, stream>>>(A, WT, bias, nullptr, nullptr, Cb, M, N, K); break;
            case 3: k_gemmB<false, false, true, true><<<g, blk, 0, stream>>>(A, WT, bias, nullptr, Cf, Cb, M, N, K); break;
        }
    };
    auto ln = [&](const float* X, const float* gg, const float* bb, u16* Ob, float* Of, int M) {
        if (Ob) k_ln<0><<<dim3(M), dim3(256), 0, stream>>>(X, gg, bb, Ob, nullptr);
        else    k_ln<1><<<dim3(M), dim3(256), 0, stream>>>(X, gg, bb, nullptr, Of);
    };
    auto attn = [&](const u16* Q, int qs, const u16* Kp, int ks2, const u16* Vp, int vs,
                    u16* O, int Tq, int Tk) {
        k_attnM<<<dim3(NB * 12), dim3(256), 0, stream>>>(Q, qs, Kp, ks2, Vp, vs, O, D, Tq, Tk);
    };

    // pre-norm transformer block; Xf fp32 residual, Xb its bf16 mirror
    auto tblock = [&](float* Xf, u16* Xb, int Mtok, int Tseq, int basei, int l, u16* const* Wl) {
        const float* ln1g = IN(basei + 0) + l * D;
        const float* ln1b = IN(basei + 1) + l * D;
        const float* bqkv = IN(basei + 3) + l * 3 * D;
        const float* bo = IN(basei + 5) + l * D;
        const float* ln2g = IN(basei + 6) + l * D;
        const float* ln2b = IN(basei + 7) + l * D;
        const float* b1 = IN(basei + 9) + l * FF;
        const float* b2 = IN(basei + 11) + l * D;

        ln(Xf, ln1g, ln1b, hb, nullptr, Mtok);
        gemm(0, hb, Wl[0], bqkv, nullptr, nullptr, s1b, Mtok, 3 * D, D);        // qkv -> bf16
        attn(s1b, 3 * D, s1b + D, 3 * D, s1b + 2 * D, 3 * D, hb, Tseq, Tseq);   // self-attn -> hb
        gemm(1, hb, Wl[1], bo, Xf, Xf, Xb, Mtok, D, D);                         // x += ao@wo+bo
        ln(Xf, ln2g, ln2b, hb, nullptr, Mtok);
        gemm(2, hb, Wl[2], b1, nullptr, nullptr, s1b, Mtok, FF, D);             // gelu -> bf16
        gemm(1, s1b, Wl[3], b2, Xf, Xf, Xb, Mtok, D, FF);                       // x += ff@w2+b2
    };

    // ---------------- encoder ----------------
    hipMemcpyAsync(x, IN(0), (long long)Menc * D * 4, hipMemcpyDeviceToDevice, stream);
    for (int l = 0; l < NL; ++l)
        tblock(x, xb, Menc, S, 5, l, encW[l]);

    // ---------------- decoder ----------------
    k_gatherB<<<dim3(Mdec), dim3(256), 0, stream>>>(spe, tpos, flagD, qb);
    u16* qq = s1b;
    u16* kk = s1b + (long long)Mdec * D;
    u16* vv = kk + (long long)Menc * D;
    for (int l = 0; l < NL; ++l) {
        gemm(0, qb, caW[l][0], IN(30) + l * D, nullptr, nullptr, qq, Mdec, D, D);
        gemm(0, xb, caW[l][1], IN(32) + l * D, nullptr, nullptr, kk, Menc, D, D);
        gemm(0, xb, caW[l][2], IN(34) + l * D, nullptr, nullptr, vv, Menc, D, D);
        attn(qq, D, kk, D, vv, D, hb, T, S);                                    // cross-attn -> hb
        gemm(3, hb, caW[l][3], IN(36) + l * D, nullptr, q, qb, Mdec, D, D);     // q = ca@wo+bo
        tblock(q, qb, Mdec, T, 17, l, decW[l]);
    }
    ln(q, norm_g, norm_b, nullptr, (float*)d_out, Mdec);
}

// Round 14
// 3451.701 us; speedup vs baseline: 34.4081x; 1.0795x over previous
//
#include <hip/hip_runtime.h>

typedef unsigned short u16;
typedef __attribute__((ext_vector_type(8))) __bf16 bf16x8;
typedef __attribute__((ext_vector_type(4))) float f32x4;

#define DEV static __device__ __forceinline__

#define ARENA_BYTES 349700096ULL
__device__ __align__(256) char g_arena[ARENA_BYTES];

DEV float bf2f(u16 u) { return __uint_as_float(((unsigned)u) << 16); }
DEV u16 f2bf(float f) {
    unsigned u = __float_as_uint(f);
    return (u16)((u + 0x7fffu + ((u >> 16) & 1u)) >> 16);
}
DEV float gelu_tanh(float x) {
    float x3 = x * x * x;
    return 0.5f * x * (1.f + tanhf(0.7978845608028654f * (x + 0.044715f * x3)));
}

// ---- async global->LDS, 16B per lane (m97 pattern; lane i -> ldsbase + i*16) ----
DEV void gload16(const u16* gp, u16* lp) {
    __builtin_amdgcn_global_load_lds((const __attribute__((address_space(1))) void*)gp,
                                     (__attribute__((address_space(3))) void*)lp, 16, 0, 0);
}

// ---- target_positions dtype sniff ----
__global__ __launch_bounds__(256) void k_detect_i64(const int* __restrict__ pos, int nhalf,
                                                    int* __restrict__ flagD) {
    int i = blockIdx.x * 256 + threadIdx.x;
    if (i < nhalf && pos[2 * i + 1] != 0) atomicAnd(flagD, 0);
}

// ---- gather rows of spatial_pos_embed -> bf16 ----
__global__ __launch_bounds__(256) void k_gatherB(const float* __restrict__ spe,
                                                 const int* __restrict__ pos,
                                                 const int* __restrict__ flagD,
                                                 u16* __restrict__ qb) {
    int row = blockIdx.x;
    int p = (*flagD) ? pos[2 * row] : pos[row];
    p = (p < 0) ? 0 : (p > 195 ? 195 : p);
    const float* src = spe + (size_t)p * 768;
    size_t o = (size_t)row * 768;
    for (int i = threadIdx.x; i < 768; i += 256) qb[o + i] = f2bf(src[i]);
}

// ---- LayerNorm over 768: fp32 in, bf16 out (OUTF32=0) or fp32 out (final) ----
template <int OUTF32>
__global__ __launch_bounds__(256) void k_ln(const float* __restrict__ X,
                                            const float* __restrict__ g,
                                            const float* __restrict__ b,
                                            u16* __restrict__ Ob, float* __restrict__ Of) {
    const int row = blockIdx.x, tid = threadIdx.x;
    const float* xr = X + (size_t)row * 768;
    float v0 = xr[tid], v1 = xr[tid + 256], v2 = xr[tid + 512];
    float s = v0 + v1 + v2, s2 = v0 * v0 + v1 * v1 + v2 * v2;
#pragma unroll
    for (int off = 32; off; off >>= 1) {
        s += __shfl_xor(s, off);
        s2 += __shfl_xor(s2, off);
    }
    __shared__ float red[8];
    const int wid = tid >> 6, lane = tid & 63;
    if (lane == 0) { red[wid] = s; red[4 + wid] = s2; }
    __syncthreads();
    s = red[0] + red[1] + red[2] + red[3];
    s2 = red[4] + red[5] + red[6] + red[7];
    const float mu = s * (1.f / 768.f);
    const float var = fmaxf(s2 * (1.f / 768.f) - mu * mu, 0.f);
    const float rs = rsqrtf(var + 1e-5f);
    size_t o = (size_t)row * 768;
#pragma unroll
    for (int i = 0; i < 3; ++i) {
        int c = tid + 256 * i;
        float vv = (i == 0 ? v0 : (i == 1 ? v1 : v2));
        float y = (vv - mu) * rs * g[c] + b[c];
        if (OUTF32) Of[o + c] = y;
        else        Ob[o + c] = f2bf(y);
    }
}

// ---- weight transpose + fp32->bf16 convert: W[K,N] -> WT[N,K] ----
__global__ __launch_bounds__(256) void k_wtrans(const float* __restrict__ W,
                                                u16* __restrict__ WT, int K, int N) {
    int idx = blockIdx.x * 256 + threadIdx.x;
    int tot = N * (K >> 3);
    if (idx >= tot) return;
    int n = idx % N;
    int kc = idx / N;
    union { u16 u[8]; int4 v; } tmp;
#pragma unroll
    for (int j = 0; j < 8; ++j) tmp.u[j] = f2bf(W[(size_t)(kc * 8 + j) * N + n]);
    *(int4*)&WT[(size_t)n * K + kc * 8] = tmp.v;
}

// ---- bf16 MFMA GEMM v2: BK=64, XOR-swizzled gload_lds staging (rule #21),
//      bijective XCD-chunked block swizzle (m204). 128x128 tile, 4 waves (2x2). ----
template <bool GELU_, bool RES_, bool OF32, bool OBF>
__global__ __launch_bounds__(256) void k_gemmB(const u16* __restrict__ A,
                                               const u16* __restrict__ BT,
                                               const float* __restrict__ bias,
                                               const float* __restrict__ R,
                                               float* __restrict__ Cf, u16* __restrict__ Cb,
                                               int M, int N, int K) {
    __shared__ __align__(16) u16 Asm[128 * 64];
    __shared__ __align__(16) u16 Bsm[128 * 64];
    const int tid = threadIdx.x;
    const int lane = tid & 63;
    const int wid = tid >> 6;
    const int wm = wid >> 1, wn = wid & 1;

    // XCD-chunked bijective swizzle; N-tile-fastest within a chunk (A-panel L2 reuse)
    const int nbx = gridDim.x, nby = gridDim.y;
    const int nwg = nbx * nby;
    const int bid = blockIdx.y * nbx + blockIdx.x;
    const int q8 = nwg >> 3, r8 = nwg & 7;
    const int xcd = bid & 7, pos = bid >> 3;
    const int swz = (xcd < r8 ? xcd * (q8 + 1) : r8 * (q8 + 1) + (xcd - r8) * q8) + pos;
    const int tyy = swz % nby;     // N-tile
    const int txx = swz / nby;     // M-tile

    const size_t Abase = (size_t)txx * 128 * K;
    const size_t Bbase = (size_t)tyy * 128 * K;

    f32x4 acc[4][4] = {};
    // staging: lane covers row (lane>>3) in its 8-row group, phys granule (lane&7);
    // global (logical) granule = (lane&7) ^ (lane>>3)  [XOR swizzle]
    const int srow = lane >> 3;
    const int sgr = (lane & 7) ^ srow;
    const int fr = lane & 15, g = lane >> 4;
    const int s7 = fr & 7;          // read-side swizzle selector (= row & 7)

    for (int k0 = 0; k0 < K; k0 += 64) {
#pragma unroll
        for (int n = 0; n < 4; ++n) {
            const int rg = wid * 32 + n * 8;
            gload16(A + Abase + (size_t)(rg + srow) * K + k0 + sgr * 8, &Asm[rg * 64]);
            gload16(BT + Bbase + (size_t)(rg + srow) * K + k0 + sgr * 8, &Bsm[rg * 64]);
        }
        __syncthreads();

#pragma unroll
        for (int kk = 0; kk < 2; ++kk) {
            const int gr8 = (((kk * 4 + g) ^ s7) << 3);
            bf16x8 af[4], bfr[4];
#pragma unroll
            for (int i = 0; i < 4; ++i)
                af[i] = *(const bf16x8*)&Asm[(wm * 64 + i * 16 + fr) * 64 + gr8];
#pragma unroll
            for (int j = 0; j < 4; ++j)
                bfr[j] = *(const bf16x8*)&Bsm[(wn * 64 + j * 16 + fr) * 64 + gr8];
#pragma unroll
            for (int i = 0; i < 4; ++i)
#pragma unroll
                for (int j = 0; j < 4; ++j)
                    acc[i][j] = __builtin_amdgcn_mfma_f32_16x16x32_bf16(af[i], bfr[j], acc[i][j], 0, 0, 0);
        }
        __syncthreads();
    }

    // C/D layout: col=lane&15, row=(lane>>4)*4+reg  [HW-verified m89/m91]
    const int g4 = (lane >> 4) * 4;
#pragma unroll
    for (int j = 0; j < 4; ++j) {
        const int col = tyy * 128 + wn * 64 + j * 16 + fr;
        const float bc = bias[col];
#pragma unroll
        for (int i = 0; i < 4; ++i) {
#pragma unroll
            for (int r = 0; r < 4; ++r) {
                const int row = txx * 128 + wm * 64 + i * 16 + g4 + r;
                float v = acc[i][j][r] + bc;
                if (GELU_) v = gelu_tanh(v);
                if (RES_)  v += R[(size_t)row * N + col];
                if (OF32)  Cf[(size_t)row * N + col] = v;
                if (OBF)   Cb[(size_t)row * N + col] = f2bf(v);
            }
        }
    }
}

// ---- MFMA flash attention, bf16 in / bf16 out (structure proven r11-r13) ----
__global__ __launch_bounds__(256) void k_attnM(const u16* __restrict__ Qp, int qs,
                                               const u16* __restrict__ Kp, int ks,
                                               const u16* __restrict__ Vp, int vs,
                                               u16* __restrict__ Op, int os,
                                               int Tq, int Tk) {
    __shared__ u16 kl[208][72];
    __shared__ u16 vt[64][272];
    __shared__ u16 pl[4][16][72];
    const int bh = blockIdx.x, b = bh / 12, h = bh % 12;
    const int tid = threadIdx.x, lane = tid & 63, wid = tid >> 6;
    const int fr = lane & 15, g = lane >> 4, g4 = g * 4;

    const int Tkp = (Tk + 15) & ~15;
    const int NC = (Tkp + 63) >> 6;
    const int TC = NC << 6;

    for (int r = wid; r < Tkp; r += 4) {
        kl[r][lane] = (r < Tk) ? Kp[((size_t)b * Tk + r) * ks + h * 64 + lane] : (u16)0;
    }
    for (int t = wid; t < TC; t += 4) {
        vt[lane][t] = (t < Tk) ? Vp[((size_t)b * Tk + t) * vs + h * 64 + lane] : (u16)0;
    }
    __syncthreads();

    const int NT = (Tq + 63) >> 6;
    for (int it = 0; it < NT; ++it) {
        const int qb = (it << 6) + (wid << 4);
        if (qb >= Tq) continue;

        int qr = qb + fr;
        if (qr >= Tq) qr = 0;
        const u16* Qrow = Qp + ((size_t)b * Tq + qr) * qs + h * 64;
        bf16x8 afq0 = *(const bf16x8*)&Qrow[g * 8];
        bf16x8 afq1 = *(const bf16x8*)&Qrow[32 + g * 8];

        f32x4 acc_o[4] = {};
        float m_r[4] = {-1e30f, -1e30f, -1e30f, -1e30f};
        float lp[4] = {0.f, 0.f, 0.f, 0.f};

        for (int c = 0; c < NC; ++c) {
            const int tk0 = c << 6;
            int NF = (Tkp - tk0) >> 4;
            if (NF > 4) NF = 4;

            f32x4 acc_s[4] = {};
#pragma unroll
            for (int nf = 0; nf < 4; ++nf) {
                if (nf < NF) {
                    const u16* kr = &kl[tk0 + nf * 16 + fr][0];
                    acc_s[nf] = __builtin_amdgcn_mfma_f32_16x16x32_bf16(
                        afq0, *(const bf16x8*)&kr[g * 8], acc_s[nf], 0, 0, 0);
                    acc_s[nf] = __builtin_amdgcn_mfma_f32_16x16x32_bf16(
                        afq1, *(const bf16x8*)&kr[32 + g * 8], acc_s[nf], 0, 0, 0);
                }
            }
            float pm[4] = {-1e30f, -1e30f, -1e30f, -1e30f};
#pragma unroll
            for (int nf = 0; nf < 4; ++nf) {
                if (nf < NF) {
                    const bool cv = (tk0 + nf * 16 + fr) < Tk;
#pragma unroll
                    for (int r = 0; r < 4; ++r) {
                        float sv = acc_s[nf][r] * 0.125f;
                        acc_s[nf][r] = sv;
                        if (cv) pm[r] = fmaxf(pm[r], sv);
                    }
                }
            }
#pragma unroll
            for (int off = 1; off < 16; off <<= 1)
#pragma unroll
                for (int r = 0; r < 4; ++r) pm[r] = fmaxf(pm[r], __shfl_xor(pm[r], off));
            float al[4];
#pragma unroll
            for (int r = 0; r < 4; ++r) {
                float mn = fmaxf(m_r[r], pm[r]);
                al[r] = __expf(m_r[r] - mn);
                m_r[r] = mn;
                lp[r] *= al[r];
            }
#pragma unroll
            for (int nfd = 0; nfd < 4; ++nfd)
#pragma unroll
                for (int r = 0; r < 4; ++r) acc_o[nfd][r] *= al[r];
#pragma unroll
            for (int nf = 0; nf < 4; ++nf) {
                const bool cv = (nf < NF) && ((tk0 + nf * 16 + fr) < Tk);
#pragma unroll
                for (int r = 0; r < 4; ++r) {
                    float w = cv ? __expf(acc_s[nf][r] - m_r[r]) : 0.f;
                    lp[r] += w;
                    pl[wid][g4 + r][nf * 16 + fr] = f2bf(w);
                }
            }
#pragma unroll
            for (int ksp = 0; ksp < 2; ++ksp) {
                bf16x8 ap = *(const bf16x8*)&pl[wid][fr][ksp * 32 + g * 8];
#pragma unroll
                for (int nfd = 0; nfd < 4; ++nfd)
                    acc_o[nfd] = __builtin_amdgcn_mfma_f32_16x16x32_bf16(
                        ap, *(const bf16x8*)&vt[nfd * 16 + fr][tk0 + ksp * 32 + g * 8],
                        acc_o[nfd], 0, 0, 0);
            }
        }
#pragma unroll
        for (int off = 1; off < 16; off <<= 1)
#pragma unroll
            for (int r = 0; r < 4; ++r) lp[r] += __shfl_xor(lp[r], off);
#pragma unroll
        for (int r = 0; r < 4; ++r) {
            int qrow = qb + g4 + r;
            if (qrow < Tq) {
                float inv = 1.f / lp[r];
#pragma unroll
                for (int nfd = 0; nfd < 4; ++nfd)
                    Op[((size_t)b * Tq + qrow) * os + h * 64 + nfd * 16 + fr] =
                        f2bf(acc_o[nfd][r] * inv);
            }
        }
    }
}

// =======================================================================================
extern "C" void kernel_launch(void* const* d_in, const int* in_sizes, int n_in,
                              void* d_out, int out_size, void* d_ws, size_t ws_size,
                              hipStream_t stream) {
    const int D = 768, FF = 3072, NB = 64, S = 196, T = 98, NL = 3;
    const int Menc = NB * S;   // 12544
    const int Mdec = NB * T;   // 6272

    auto IN = [&](int i) { return (const float*)d_in[i]; };
    const int* tpos = (const int*)d_in[1];
    const float* spe = IN(2);
    const float* norm_g = IN(3);
    const float* norm_b = IN(4);

    char* base;
    if (ws_size >= ARENA_BYTES) {
        base = (char*)d_ws;
    } else {
        void* sym = nullptr;
        if (hipGetSymbolAddress(&sym, HIP_SYMBOL(g_arena)) == hipSuccess && sym)
            base = (char*)sym;
        else
            base = (char*)d_ws;
    }
    char* pp = base;
    auto alloc = [&](long long bytes) -> void* {
        void* r = (void*)pp;
        pp += (bytes + 255) & ~255LL;
        return r;
    };
    int* flag = (int*)alloc(256);
    int* flagD = flag + 1;

    // ---- one-time weight pre-conversion: W[K,N] fp32 -> WT[N,K] bf16 ----
    auto cvw = [&](const float* W, int K, int N) -> u16* {
        u16* dst = (u16*)alloc((long long)K * N * 2);
        int tot = N * (K / 8);
        k_wtrans<<<dim3((tot + 255) / 256), dim3(256), 0, stream>>>(W, dst, K, N);
        return dst;
    };
    u16 *encW[3][4], *decW[3][4], *caWq[3], *caWo[3], *caWkv[3];
    float* bkv[3];
    for (int l = 0; l < NL; ++l) {
        encW[l][0] = cvw(IN(7) + (long long)l * D * 3 * D, D, 3 * D);
        encW[l][1] = cvw(IN(9) + (long long)l * D * D, D, D);
        encW[l][2] = cvw(IN(13) + (long long)l * D * FF, D, FF);
        encW[l][3] = cvw(IN(15) + (long long)l * FF * D, FF, D);
    }
    for (int l = 0; l < NL; ++l) {
        decW[l][0] = cvw(IN(19) + (long long)l * D * 3 * D, D, 3 * D);
        decW[l][1] = cvw(IN(21) + (long long)l * D * D, D, D);
        decW[l][2] = cvw(IN(25) + (long long)l * D * FF, D, FF);
        decW[l][3] = cvw(IN(27) + (long long)l * FF * D, FF, D);
    }
    for (int l = 0; l < NL; ++l) {
        caWq[l] = cvw(IN(29) + (long long)l * D * D, D, D);
        // fused wk|wv: WT[1536][768] (rows 0..767 = wk^T, 768..1535 = wv^T)
        caWkv[l] = (u16*)alloc((long long)2 * D * D * 2);
        {
            int tot = D * (D / 8);
            k_wtrans<<<dim3((tot + 255) / 256), dim3(256), 0, stream>>>(
                IN(31) + (long long)l * D * D, caWkv[l], D, D);
            k_wtrans<<<dim3((tot + 255) / 256), dim3(256), 0, stream>>>(
                IN(33) + (long long)l * D * D, caWkv[l] + (long long)D * D, D, D);
        }
        bkv[l] = (float*)alloc(2 * D * 4);
        hipMemcpyAsync(bkv[l], IN(32) + l * D, D * 4, hipMemcpyDeviceToDevice, stream);
        hipMemcpyAsync(bkv[l] + D, IN(34) + l * D, D * 4, hipMemcpyDeviceToDevice, stream);
        caWo[l] = cvw(IN(35) + (long long)l * D * D, D, D);
    }

    float* x = (float*)alloc((long long)Menc * D * 4);   // fp32 residual (enc)
    float* q = (float*)alloc((long long)Mdec * D * 4);   // fp32 residual (dec)
    u16* xb = (u16*)alloc((long long)Menc * D * 2);      // bf16 mirror of x
    u16* qb = (u16*)alloc((long long)Mdec * D * 2);      // bf16 mirror of q
    u16* hb = (u16*)alloc((long long)Menc * D * 2);      // bf16 LN/attn out
    u16* s1b = (u16*)alloc((long long)Menc * FF * 2);    // bf16 qkv / ff1 / dec qq,kkvv

    hipMemsetAsync(flagD, 0x01, 4, stream);
    k_detect_i64<<<dim3((Mdec / 2 + 255) / 256), dim3(256), 0, stream>>>(tpos, Mdec / 2, flagD);

    // modes: 0 plain->bf16 | 1 res->fp32+bf16 | 2 gelu->bf16 | 3 plain->fp32+bf16
    auto gemm = [&](int mode, const u16* A, const u16* WT, const float* bias,
                    const float* R, float* Cf, u16* Cb, int M, int N, int K) {
        dim3 g(M / 128, N / 128), blk(256);
        switch (mode) {
            case 0: k_gemmB<false, false, false, true><<<g, blk, 0, stream>>>(A, WT, bias, nullptr, nullptr, Cb, M, N, K); break;
            case 1: k_gemmB<false, true, true, true><<<g, blk, 0, stream>>>(A, WT, bias, R, Cf, Cb, M, N, K); break;
            case 2: k_gemmB<true, false, false, true><<<g, blk, 0, stream>>>(A, WT, bias, nullptr, nullptr, Cb, M, N, K); break;
            case 3: k_gemmB<false, false, true, true><<<g, blk, 0, stream>>>(A, WT, bias, nullptr, Cf, Cb, M, N, K); break;
        }
    };
    auto ln = [&](const float* X, const float* gg, const float* bb, u16* Ob, float* Of, int M) {
        if (Ob) k_ln<0><<<dim3(M), dim3(256), 0, stream>>>(X, gg, bb, Ob, nullptr);
        else    k_ln<1><<<dim3(M), dim3(256), 0, stream>>>(X, gg, bb, nullptr, Of);
    };
    auto attn = [&](const u16* Q, int qs, const u16* Kp, int ks2, const u16* Vp, int vs,
                    u16* O, int Tq, int Tk) {
        k_attnM<<<dim3(NB * 12), dim3(256), 0, stream>>>(Q, qs, Kp, ks2, Vp, vs, O, D, Tq, Tk);
    };

    // pre-norm transformer block; Xf fp32 residual, Xb its bf16 mirror
    auto tblock = [&](float* Xf, u16* Xb, int Mtok, int Tseq, int basei, int l, u16* const* Wl) {
        const float* ln1g = IN(basei + 0) + l * D;
        const float* ln1b = IN(basei + 1) + l * D;
        const float* bqkv = IN(basei + 3) + l * 3 * D;
        const float* bo = IN(basei + 5) + l * D;
        const float* ln2g = IN(basei + 6) + l * D;
        const float* ln2b = IN(basei + 7) + l * D;
        const float* b1 = IN(basei + 9) + l * FF;
        const float* b2 = IN(basei + 11) + l * D;

        ln(Xf, ln1g, ln1b, hb, nullptr, Mtok);
        gemm(0, hb, Wl[0], bqkv, nullptr, nullptr, s1b, Mtok, 3 * D, D);        // qkv -> bf16
        attn(s1b, 3 * D, s1b + D, 3 * D, s1b + 2 * D, 3 * D, hb, Tseq, Tseq);   // self-attn -> hb
        gemm(1, hb, Wl[1], bo, Xf, Xf, Xb, Mtok, D, D);                         // x += ao@wo+bo
        ln(Xf, ln2g, ln2b, hb, nullptr, Mtok);
        gemm(2, hb, Wl[2], b1, nullptr, nullptr, s1b, Mtok, FF, D);             // gelu -> bf16
        gemm(1, s1b, Wl[3], b2, Xf, Xf, Xb, Mtok, D, FF);                       // x += ff@w2+b2
    };

    // ---------------- encoder ----------------
    hipMemcpyAsync(x, IN(0), (long long)Menc * D * 4, hipMemcpyDeviceToDevice, stream);
    for (int l = 0; l < NL; ++l)
        tblock(x, xb, Menc, S, 5, l, encW[l]);

    // ---------------- decoder ----------------
    k_gatherB<<<dim3(Mdec), dim3(256), 0, stream>>>(spe, tpos, flagD, qb);
    u16* qq = s1b;                                       // [Mdec, D]
    u16* kkvv = s1b + (long long)Mdec * D;               // [Menc, 1536] (kk | vv)
    for (int l = 0; l < NL; ++l) {
        gemm(0, qb, caWq[l], IN(30) + l * D, nullptr, nullptr, qq, Mdec, D, D);
        gemm(0, xb, caWkv[l], bkv[l], nullptr, nullptr, kkvv, Menc, 2 * D, D);  // kk|vv fused
        attn(qq, D, kkvv, 2 * D, kkvv + D, 2 * D, hb, T, S);                    // cross-attn
        gemm(3, hb, caWo[l], IN(36) + l * D, nullptr, q, qb, Mdec, D, D);       // q = ca@wo+bo
        tblock(q, qb, Mdec, T, 17, l, decW[l]);
    }
    ln(q, norm_g, norm_b, nullptr, (float*)d_out, Mdec);
}

// Round 15
// 3053.175 us; speedup vs baseline: 38.8994x; 1.1305x over previous
//
#include <hip/hip_runtime.h>

typedef unsigned short u16;
typedef __attribute__((ext_vector_type(8))) __bf16 bf16x8;
typedef __attribute__((ext_vector_type(4))) float f32x4;

#define DEV static __device__ __forceinline__

#define ARENA_BYTES 349700096ULL
__device__ __align__(256) char g_arena[ARENA_BYTES];

DEV float bf2f(u16 u) { return __uint_as_float(((unsigned)u) << 16); }
DEV u16 f2bf(float f) {
    unsigned u = __float_as_uint(f);
    return (u16)((u + 0x7fffu + ((u >> 16) & 1u)) >> 16);
}
DEV float gelu_tanh(float x) {
    float x3 = x * x * x;
    return 0.5f * x * (1.f + tanhf(0.7978845608028654f * (x + 0.044715f * x3)));
}

// ---- async global->LDS, 16B per lane (m97 pattern; lane i -> ldsbase + i*16) ----
DEV void gload16(const u16* gp, u16* lp) {
    __builtin_amdgcn_global_load_lds((const __attribute__((address_space(1))) void*)gp,
                                     (__attribute__((address_space(3))) void*)lp, 16, 0, 0);
}

// ---- target_positions dtype sniff ----
__global__ __launch_bounds__(256) void k_detect_i64(const int* __restrict__ pos, int nhalf,
                                                    int* __restrict__ flagD) {
    int i = blockIdx.x * 256 + threadIdx.x;
    if (i < nhalf && pos[2 * i + 1] != 0) atomicAnd(flagD, 0);
}

// ---- gather rows of spatial_pos_embed -> bf16 ----
__global__ __launch_bounds__(256) void k_gatherB(const float* __restrict__ spe,
                                                 const int* __restrict__ pos,
                                                 const int* __restrict__ flagD,
                                                 u16* __restrict__ qb) {
    int row = blockIdx.x;
    int p = (*flagD) ? pos[2 * row] : pos[row];
    p = (p < 0) ? 0 : (p > 195 ? 195 : p);
    const float* src = spe + (size_t)p * 768;
    size_t o = (size_t)row * 768;
    for (int i = threadIdx.x; i < 768; i += 256) qb[o + i] = f2bf(src[i]);
}

// ---- LayerNorm over 768: fp32 in, bf16 out (OUTF32=0) or fp32 out (final) ----
template <int OUTF32>
__global__ __launch_bounds__(256) void k_ln(const float* __restrict__ X,
                                            const float* __restrict__ g,
                                            const float* __restrict__ b,
                                            u16* __restrict__ Ob, float* __restrict__ Of) {
    const int row = blockIdx.x, tid = threadIdx.x;
    const float* xr = X + (size_t)row * 768;
    float v0 = xr[tid], v1 = xr[tid + 256], v2 = xr[tid + 512];
    float s = v0 + v1 + v2, s2 = v0 * v0 + v1 * v1 + v2 * v2;
#pragma unroll
    for (int off = 32; off; off >>= 1) {
        s += __shfl_xor(s, off);
        s2 += __shfl_xor(s2, off);
    }
    __shared__ float red[8];
    const int wid = tid >> 6, lane = tid & 63;
    if (lane == 0) { red[wid] = s; red[4 + wid] = s2; }
    __syncthreads();
    s = red[0] + red[1] + red[2] + red[3];
    s2 = red[4] + red[5] + red[6] + red[7];
    const float mu = s * (1.f / 768.f);
    const float var = fmaxf(s2 * (1.f / 768.f) - mu * mu, 0.f);
    const float rs = rsqrtf(var + 1e-5f);
    size_t o = (size_t)row * 768;
#pragma unroll
    for (int i = 0; i < 3; ++i) {
        int c = tid + 256 * i;
        float vv = (i == 0 ? v0 : (i == 1 ? v1 : v2));
        float y = (vv - mu) * rs * g[c] + b[c];
        if (OUTF32) Of[o + c] = y;
        else        Ob[o + c] = f2bf(y);
    }
}

// ---- weight transpose + fp32->bf16 convert: W[K,N] -> WT[N,K] ----
__global__ __launch_bounds__(256) void k_wtrans(const float* __restrict__ W,
                                                u16* __restrict__ WT, int K, int N) {
    int idx = blockIdx.x * 256 + threadIdx.x;
    int tot = N * (K >> 3);
    if (idx >= tot) return;
    int n = idx % N;
    int kc = idx / N;
    union { u16 u[8]; int4 v; } tmp;
#pragma unroll
    for (int j = 0; j < 8; ++j) tmp.u[j] = f2bf(W[(size_t)(kc * 8 + j) * N + n]);
    *(int4*)&WT[(size_t)n * K + kc * 8] = tmp.v;
}

// ---- bf16 MFMA GEMM v3: BK=64, DOUBLE-BUFFERED LDS + 2-phase prefetch (T3/T4 minimum),
//      XOR-swizzled gload_lds staging (rule #21, proven r14), bijective XCD block swizzle.
//      128x128 tile, 4 waves (2x2); one barrier per K-step; loads in flight over MFMAs. ----
template <bool GELU_, bool RES_, bool OF32, bool OBF>
__global__ __launch_bounds__(256) void k_gemmB(const u16* __restrict__ A,
                                               const u16* __restrict__ BT,
                                               const float* __restrict__ bias,
                                               const float* __restrict__ R,
                                               float* __restrict__ Cf, u16* __restrict__ Cb,
                                               int M, int N, int K) {
    __shared__ __align__(16) u16 Asm[2][128 * 64];
    __shared__ __align__(16) u16 Bsm[2][128 * 64];
    const int tid = threadIdx.x;
    const int lane = tid & 63;
    const int wid = tid >> 6;
    const int wm = wid >> 1, wn = wid & 1;

    // XCD-chunked bijective swizzle; N-tile-fastest within a chunk (A-panel L2 reuse)
    const int nbx = gridDim.x, nby = gridDim.y;
    const int nwg = nbx * nby;
    const int bid = blockIdx.y * nbx + blockIdx.x;
    const int q8 = nwg >> 3, r8 = nwg & 7;
    const int xcd = bid & 7, pos = bid >> 3;
    const int swz = (xcd < r8 ? xcd * (q8 + 1) : r8 * (q8 + 1) + (xcd - r8) * q8) + pos;
    const int tyy = swz % nby;     // N-tile
    const int txx = swz / nby;     // M-tile

    // staging: lane covers row (lane>>3) in its 8-row group, phys granule (lane&7);
    // global (logical) granule = (lane&7) ^ (lane>>3)  [XOR swizzle, bit-exact r14]
    const int srow = lane >> 3;
    const int sgr = (lane & 7) ^ srow;
    const int fr = lane & 15, g = lane >> 4;
    const int s7 = fr & 7;          // read-side swizzle selector (= row & 7)

    const u16* Ab = A + (size_t)txx * 128 * K + (size_t)srow * K + sgr * 8;
    const u16* Bb = BT + (size_t)tyy * 128 * K + (size_t)srow * K + sgr * 8;

    f32x4 acc[4][4] = {};
    const int nIter = K >> 6;

    // prologue: stage tile 0 into buffer 0
#pragma unroll
    for (int n = 0; n < 4; ++n) {
        const int rg = wid * 32 + n * 8;
        gload16(Ab + (size_t)rg * K, &Asm[0][rg * 64]);
        gload16(Bb + (size_t)rg * K, &Bsm[0][rg * 64]);
    }
    __syncthreads();                         // drains vmcnt -> buf0 valid

    int cur = 0;
    for (int t = 0; t < nIter; ++t) {
        // phase 1: issue next tile's loads into the other buffer (latency hides under MFMA)
        if (t + 1 < nIter) {
            const int k0 = (t + 1) << 6;
#pragma unroll
            for (int n = 0; n < 4; ++n) {
                const int rg = wid * 32 + n * 8;
                gload16(Ab + (size_t)rg * K + k0, &Asm[cur ^ 1][rg * 64]);
                gload16(Bb + (size_t)rg * K + k0, &Bsm[cur ^ 1][rg * 64]);
            }
        }
        // phase 2: compute from current buffer
        const u16* As = &Asm[cur][0];
        const u16* Bs = &Bsm[cur][0];
#pragma unroll
        for (int kk = 0; kk < 2; ++kk) {
            const int gr8 = (((kk * 4 + g) ^ s7) << 3);
            bf16x8 af[4], bfr[4];
#pragma unroll
            for (int i = 0; i < 4; ++i)
                af[i] = *(const bf16x8*)&As[(wm * 64 + i * 16 + fr) * 64 + gr8];
#pragma unroll
            for (int j = 0; j < 4; ++j)
                bfr[j] = *(const bf16x8*)&Bs[(wn * 64 + j * 16 + fr) * 64 + gr8];
#pragma unroll
            for (int i = 0; i < 4; ++i)
#pragma unroll
                for (int j = 0; j < 4; ++j)
                    acc[i][j] = __builtin_amdgcn_mfma_f32_16x16x32_bf16(af[i], bfr[j], acc[i][j], 0, 0, 0);
        }
        __syncthreads();                     // drain: next-tile loads + all reads of cur done
        cur ^= 1;
    }

    // C/D layout: col=lane&15, row=(lane>>4)*4+reg  [HW-verified m89/m91]
    const int g4 = (lane >> 4) * 4;
#pragma unroll
    for (int j = 0; j < 4; ++j) {
        const int col = tyy * 128 + wn * 64 + j * 16 + fr;
        const float bc = bias[col];
#pragma unroll
        for (int i = 0; i < 4; ++i) {
#pragma unroll
            for (int r = 0; r < 4; ++r) {
                const int row = txx * 128 + wm * 64 + i * 16 + g4 + r;
                float v = acc[i][j][r] + bc;
                if (GELU_) v = gelu_tanh(v);
                if (RES_)  v += R[(size_t)row * N + col];
                if (OF32)  Cf[(size_t)row * N + col] = v;
                if (OBF)   Cb[(size_t)row * N + col] = f2bf(v);
            }
        }
    }
}

// ---- MFMA flash attention, bf16 in / bf16 out (structure proven r11-r14) ----
__global__ __launch_bounds__(256) void k_attnM(const u16* __restrict__ Qp, int qs,
                                               const u16* __restrict__ Kp, int ks,
                                               const u16* __restrict__ Vp, int vs,
                                               u16* __restrict__ Op, int os,
                                               int Tq, int Tk) {
    __shared__ u16 kl[208][72];
    __shared__ u16 vt[64][272];
    __shared__ u16 pl[4][16][72];
    const int bh = blockIdx.x, b = bh / 12, h = bh % 12;
    const int tid = threadIdx.x, lane = tid & 63, wid = tid >> 6;
    const int fr = lane & 15, g = lane >> 4, g4 = g * 4;

    const int Tkp = (Tk + 15) & ~15;
    const int NC = (Tkp + 63) >> 6;
    const int TC = NC << 6;

    for (int r = wid; r < Tkp; r += 4) {
        kl[r][lane] = (r < Tk) ? Kp[((size_t)b * Tk + r) * ks + h * 64 + lane] : (u16)0;
    }
    for (int t = wid; t < TC; t += 4) {
        vt[lane][t] = (t < Tk) ? Vp[((size_t)b * Tk + t) * vs + h * 64 + lane] : (u16)0;
    }
    __syncthreads();

    const int NT = (Tq + 63) >> 6;
    for (int it = 0; it < NT; ++it) {
        const int qb = (it << 6) + (wid << 4);
        if (qb >= Tq) continue;

        int qr = qb + fr;
        if (qr >= Tq) qr = 0;
        const u16* Qrow = Qp + ((size_t)b * Tq + qr) * qs + h * 64;
        bf16x8 afq0 = *(const bf16x8*)&Qrow[g * 8];
        bf16x8 afq1 = *(const bf16x8*)&Qrow[32 + g * 8];

        f32x4 acc_o[4] = {};
        float m_r[4] = {-1e30f, -1e30f, -1e30f, -1e30f};
        float lp[4] = {0.f, 0.f, 0.f, 0.f};

        for (int c = 0; c < NC; ++c) {
            const int tk0 = c << 6;
            int NF = (Tkp - tk0) >> 4;
            if (NF > 4) NF = 4;

            f32x4 acc_s[4] = {};
#pragma unroll
            for (int nf = 0; nf < 4; ++nf) {
                if (nf < NF) {
                    const u16* kr = &kl[tk0 + nf * 16 + fr][0];
                    acc_s[nf] = __builtin_amdgcn_mfma_f32_16x16x32_bf16(
                        afq0, *(const bf16x8*)&kr[g * 8], acc_s[nf], 0, 0, 0);
                    acc_s[nf] = __builtin_amdgcn_mfma_f32_16x16x32_bf16(
                        afq1, *(const bf16x8*)&kr[32 + g * 8], acc_s[nf], 0, 0, 0);
                }
            }
            float pm[4] = {-1e30f, -1e30f, -1e30f, -1e30f};
#pragma unroll
            for (int nf = 0; nf < 4; ++nf) {
                if (nf < NF) {
                    const bool cv = (tk0 + nf * 16 + fr) < Tk;
#pragma unroll
                    for (int r = 0; r < 4; ++r) {
                        float sv = acc_s[nf][r] * 0.125f;
                        acc_s[nf][r] = sv;
                        if (cv) pm[r] = fmaxf(pm[r], sv);
                    }
                }
            }
#pragma unroll
            for (int off = 1; off < 16; off <<= 1)
#pragma unroll
                for (int r = 0; r < 4; ++r) pm[r] = fmaxf(pm[r], __shfl_xor(pm[r], off));
            float al[4];
#pragma unroll
            for (int r = 0; r < 4; ++r) {
                float mn = fmaxf(m_r[r], pm[r]);
                al[r] = __expf(m_r[r] - mn);
                m_r[r] = mn;
                lp[r] *= al[r];
            }
#pragma unroll
            for (int nfd = 0; nfd < 4; ++nfd)
#pragma unroll
                for (int r = 0; r < 4; ++r) acc_o[nfd][r] *= al[r];
#pragma unroll
            for (int nf = 0; nf < 4; ++nf) {
                const bool cv = (nf < NF) && ((tk0 + nf * 16 + fr) < Tk);
#pragma unroll
                for (int r = 0; r < 4; ++r) {
                    float w = cv ? __expf(acc_s[nf][r] - m_r[r]) : 0.f;
                    lp[r] += w;
                    pl[wid][g4 + r][nf * 16 + fr] = f2bf(w);
                }
            }
#pragma unroll
            for (int ksp = 0; ksp < 2; ++ksp) {
                bf16x8 ap = *(const bf16x8*)&pl[wid][fr][ksp * 32 + g * 8];
#pragma unroll
                for (int nfd = 0; nfd < 4; ++nfd)
                    acc_o[nfd] = __builtin_amdgcn_mfma_f32_16x16x32_bf16(
                        ap, *(const bf16x8*)&vt[nfd * 16 + fr][tk0 + ksp * 32 + g * 8],
                        acc_o[nfd], 0, 0, 0);
            }
        }
#pragma unroll
        for (int off = 1; off < 16; off <<= 1)
#pragma unroll
            for (int r = 0; r < 4; ++r) lp[r] += __shfl_xor(lp[r], off);
#pragma unroll
        for (int r = 0; r < 4; ++r) {
            int qrow = qb + g4 + r;
            if (qrow < Tq) {
                float inv = 1.f / lp[r];
#pragma unroll
                for (int nfd = 0; nfd < 4; ++nfd)
                    Op[((size_t)b * Tq + qrow) * os + h * 64 + nfd * 16 + fr] =
                        f2bf(acc_o[nfd][r] * inv);
            }
        }
    }
}

// =======================================================================================
extern "C" void kernel_launch(void* const* d_in, const int* in_sizes, int n_in,
                              void* d_out, int out_size, void* d_ws, size_t ws_size,
                              hipStream_t stream) {
    const int D = 768, FF = 3072, NB = 64, S = 196, T = 98, NL = 3;
    const int Menc = NB * S;   // 12544
    const int Mdec = NB * T;   // 6272

    auto IN = [&](int i) { return (const float*)d_in[i]; };
    const int* tpos = (const int*)d_in[1];
    const float* spe = IN(2);
    const float* norm_g = IN(3);
    const float* norm_b = IN(4);

    char* base;
    if (ws_size >= ARENA_BYTES) {
        base = (char*)d_ws;
    } else {
        void* sym = nullptr;
        if (hipGetSymbolAddress(&sym, HIP_SYMBOL(g_arena)) == hipSuccess && sym)
            base = (char*)sym;
        else
            base = (char*)d_ws;
    }
    char* pp = base;
    auto alloc = [&](long long bytes) -> void* {
        void* r = (void*)pp;
        pp += (bytes + 255) & ~255LL;
        return r;
    };
    int* flag = (int*)alloc(256);
    int* flagD = flag + 1;

    // ---- one-time weight pre-conversion: W[K,N] fp32 -> WT[N,K] bf16 ----
    auto cvw = [&](const float* W, int K, int N) -> u16* {
        u16* dst = (u16*)alloc((long long)K * N * 2);
        int tot = N * (K / 8);
        k_wtrans<<<dim3((tot + 255) / 256), dim3(256), 0, stream>>>(W, dst, K, N);
        return dst;
    };
    u16 *encW[3][4], *decW[3][4], *caWq[3], *caWo[3], *caWkv[3];
    float* bkv[3];
    for (int l = 0; l < NL; ++l) {
        encW[l][0] = cvw(IN(7) + (long long)l * D * 3 * D, D, 3 * D);
        encW[l][1] = cvw(IN(9) + (long long)l * D * D, D, D);
        encW[l][2] = cvw(IN(13) + (long long)l * D * FF, D, FF);
        encW[l][3] = cvw(IN(15) + (long long)l * FF * D, FF, D);
    }
    for (int l = 0; l < NL; ++l) {
        decW[l][0] = cvw(IN(19) + (long long)l * D * 3 * D, D, 3 * D);
        decW[l][1] = cvw(IN(21) + (long long)l * D * D, D, D);
        decW[l][2] = cvw(IN(25) + (long long)l * D * FF, D, FF);
        decW[l][3] = cvw(IN(27) + (long long)l * FF * D, FF, D);
    }
    for (int l = 0; l < NL; ++l) {
        caWq[l] = cvw(IN(29) + (long long)l * D * D, D, D);
        caWkv[l] = (u16*)alloc((long long)2 * D * D * 2);
        {
            int tot = D * (D / 8);
            k_wtrans<<<dim3((tot + 255) / 256), dim3(256), 0, stream>>>(
                IN(31) + (long long)l * D * D, caWkv[l], D, D);
            k_wtrans<<<dim3((tot + 255) / 256), dim3(256), 0, stream>>>(
                IN(33) + (long long)l * D * D, caWkv[l] + (long long)D * D, D, D);
        }
        bkv[l] = (float*)alloc(2 * D * 4);
        hipMemcpyAsync(bkv[l], IN(32) + l * D, D * 4, hipMemcpyDeviceToDevice, stream);
        hipMemcpyAsync(bkv[l] + D, IN(34) + l * D, D * 4, hipMemcpyDeviceToDevice, stream);
        caWo[l] = cvw(IN(35) + (long long)l * D * D, D, D);
    }

    float* x = (float*)alloc((long long)Menc * D * 4);   // fp32 residual (enc)
    float* q = (float*)alloc((long long)Mdec * D * 4);   // fp32 residual (dec)
    u16* xb = (u16*)alloc((long long)Menc * D * 2);      // bf16 mirror of x
    u16* qb = (u16*)alloc((long long)Mdec * D * 2);      // bf16 mirror of q
    u16* hb = (u16*)alloc((long long)Menc * D * 2);      // bf16 LN/attn out
    u16* s1b = (u16*)alloc((long long)Menc * FF * 2);    // bf16 qkv / ff1 / dec qq,kkvv

    hipMemsetAsync(flagD, 0x01, 4, stream);
    k_detect_i64<<<dim3((Mdec / 2 + 255) / 256), dim3(256), 0, stream>>>(tpos, Mdec / 2, flagD);

    // modes: 0 plain->bf16 | 1 res->fp32+bf16 | 2 gelu->bf16 | 3 plain->fp32+bf16
    auto gemm = [&](int mode, const u16* A, const u16* WT, const float* bias,
                    const float* R, float* Cf, u16* Cb, int M, int N, int K) {
        dim3 g(M / 128, N / 128), blk(256);
        switch (mode) {
            case 0: k_gemmB<false, false, false, true><<<g, blk, 0, stream>>>(A, WT, bias, nullptr, nullptr, Cb, M, N, K); break;
            case 1: k_gemmB<false, true, true, true><<<g, blk, 0, stream>>>(A, WT, bias, R, Cf, Cb, M, N, K); break;
            case 2: k_gemmB<true, false, false, true><<<g, blk, 0, stream>>>(A, WT, bias, nullptr, nullptr, Cb, M, N, K); break;
            case 3: k_gemmB<false, false, true, true><<<g, blk, 0, stream>>>(A, WT, bias, nullptr, Cf, Cb, M, N, K); break;
        }
    };
    auto ln = [&](const float* X, const float* gg, const float* bb, u16* Ob, float* Of, int M) {
        if (Ob) k_ln<0><<<dim3(M), dim3(256), 0, stream>>>(X, gg, bb, Ob, nullptr);
        else    k_ln<1><<<dim3(M), dim3(256), 0, stream>>>(X, gg, bb, nullptr, Of);
    };
    auto attn = [&](const u16* Q, int qs, const u16* Kp, int ks2, const u16* Vp, int vs,
                    u16* O, int Tq, int Tk) {
        k_attnM<<<dim3(NB * 12), dim3(256), 0, stream>>>(Q, qs, Kp, ks2, Vp, vs, O, D, Tq, Tk);
    };

    // pre-norm transformer block; Xf fp32 residual, Xb its bf16 mirror
    auto tblock = [&](float* Xf, u16* Xb, int Mtok, int Tseq, int basei, int l, u16* const* Wl) {
        const float* ln1g = IN(basei + 0) + l * D;
        const float* ln1b = IN(basei + 1) + l * D;
        const float* bqkv = IN(basei + 3) + l * 3 * D;
        const float* bo = IN(basei + 5) + l * D;
        const float* ln2g = IN(basei + 6) + l * D;
        const float* ln2b = IN(basei + 7) + l * D;
        const float* b1 = IN(basei + 9) + l * FF;
        const float* b2 = IN(basei + 11) + l * D;

        ln(Xf, ln1g, ln1b, hb, nullptr, Mtok);
        gemm(0, hb, Wl[0], bqkv, nullptr, nullptr, s1b, Mtok, 3 * D, D);        // qkv -> bf16
        attn(s1b, 3 * D, s1b + D, 3 * D, s1b + 2 * D, 3 * D, hb, Tseq, Tseq);   // self-attn -> hb
        gemm(1, hb, Wl[1], bo, Xf, Xf, Xb, Mtok, D, D);                         // x += ao@wo+bo
        ln(Xf, ln2g, ln2b, hb, nullptr, Mtok);
        gemm(2, hb, Wl[2], b1, nullptr, nullptr, s1b, Mtok, FF, D);             // gelu -> bf16
        gemm(1, s1b, Wl[3], b2, Xf, Xf, Xb, Mtok, D, FF);                       // x += ff@w2+b2
    };

    // ---------------- encoder ----------------
    hipMemcpyAsync(x, IN(0), (long long)Menc * D * 4, hipMemcpyDeviceToDevice, stream);
    for (int l = 0; l < NL; ++l)
        tblock(x, xb, Menc, S, 5, l, encW[l]);

    // ---------------- decoder ----------------
    k_gatherB<<<dim3(Mdec), dim3(256), 0, stream>>>(spe, tpos, flagD, qb);
    u16* qq = s1b;                                       // [Mdec, D]
    u16* kkvv = s1b + (long long)Mdec * D;               // [Menc, 1536] (kk | vv)
    for (int l = 0; l < NL; ++l) {
        gemm(0, qb, caWq[l], IN(30) + l * D, nullptr, nullptr, qq, Mdec, D, D);
        gemm(0, xb, caWkv[l], bkv[l], nullptr, nullptr, kkvv, Menc, 2 * D, D);  // kk|vv fused
        attn(qq, D, kkvv, 2 * D, kkvv + D, 2 * D, hb, T, S);                    // cross-attn
        gemm(3, hb, caWo[l], IN(36) + l * D, nullptr, q, qb, Mdec, D, D);       // q = ca@wo+bo
        tblock(q, qb, Mdec, T, 17, l, decW[l]);
    }
    ln(q, norm_g, norm_b, nullptr, (float*)d_out, Mdec);
}